// Round 2
// baseline (737.230 us; speedup 1.0000x reference)
//
#include <hip/hip_runtime.h>
#include <hip/hip_bf16.h>

#define N_NODES 100000
#define N_EDGES 1600000
#define IN_DIM 128
#define HID 64
#define OUT_DIM 32
#define LN_EPS 1e-5f

// ---------- Edge dtype detect: int64 (high words all 0) vs int32 ------------
__global__ void detect_edges(const int* __restrict__ w, int* __restrict__ flag) {
  __shared__ int any;
  if (threadIdx.x == 0) any = 0;
  __syncthreads();
  if (w[2 * threadIdx.x + 1] != 0) any = 1;  // benign race, all write 1
  __syncthreads();
  if (threadIdx.x == 0) flag[0] = any ? 0 : 1;  // 1 => int64 layout
}

__global__ __launch_bounds__(256) void convert_edges(
    const int* __restrict__ w, const int* __restrict__ flag,
    int* __restrict__ srcI, int* __restrict__ dstI) {
  const int i64 = flag[0];
  for (int i = blockIdx.x * 256 + threadIdx.x; i < N_EDGES;
       i += gridDim.x * 256) {
    if (i64) {
      srcI[i] = w[2 * i];                  // low word of int64 src
      dstI[i] = w[2 * N_EDGES + 2 * i];    // low word of int64 dst
    } else {
      srcI[i] = w[i];
      dstI[i] = w[N_EDGES + i];
    }
  }
}

// ---------------- Layer 0 GEMM: p0 = x @ Wneigh0 ; s0b = x @ Wself0 + b0 ----
// fp32 everywhere. 16 rows/block, 256 threads, W staged in LDS in 2 k-chunks.
__global__ __launch_bounds__(256) void gemm0(
    const float* __restrict__ x, const float* __restrict__ Wself,
    const float* __restrict__ Wneigh, const float* __restrict__ b0,
    float* __restrict__ p0, float* __restrict__ s0b) {
  __shared__ float lws[64 * HID];   // 16 KB (k-chunk of 64)
  __shared__ float lwn[64 * HID];   // 16 KB
  __shared__ float xt[16][IN_DIM];  // 8 KB
  const int tid = threadIdx.x;
  const int row0 = blockIdx.x * 16;
  for (int i = tid; i < 16 * IN_DIM; i += 256) {
    int r = i >> 7, k = i & (IN_DIM - 1);
    int gr = row0 + r;
    xt[r][k] = (gr < N_NODES) ? x[(size_t)gr * IN_DIM + k] : 0.f;
  }
  const int c = tid & 63;
  const int rr = tid >> 6;  // 0..3
  float an[4] = {0.f, 0.f, 0.f, 0.f};
  float as[4] = {0.f, 0.f, 0.f, 0.f};
  for (int kc = 0; kc < 2; ++kc) {
    __syncthreads();
    for (int i = tid; i < 64 * HID; i += 256) {
      lws[i] = Wself[kc * 64 * HID + i];
      lwn[i] = Wneigh[kc * 64 * HID + i];
    }
    __syncthreads();
#pragma unroll 4
    for (int k = 0; k < 64; ++k) {
      const float wn = lwn[k * HID + c];
      const float ws = lws[k * HID + c];
#pragma unroll
      for (int q = 0; q < 4; ++q) {
        const float xv = xt[q * 4 + rr][kc * 64 + k];
        an[q] += xv * wn;
        as[q] += xv * ws;
      }
    }
  }
  const float bias = b0[c];
#pragma unroll
  for (int q = 0; q < 4; ++q) {
    const int gr = row0 + q * 4 + rr;
    if (gr < N_NODES) {
      p0[(size_t)gr * HID + c] = an[q];
      s0b[(size_t)gr * HID + c] = as[q] + bias;
    }
  }
}

// ---------------- Layer 1 GEMM: p1 = h1 @ Wneigh1 ; s1b = h1 @ Wself1 + b1 --
__global__ __launch_bounds__(256) void gemm1(
    const float* __restrict__ h1, const float* __restrict__ Wself,
    const float* __restrict__ Wneigh, const float* __restrict__ b1,
    float* __restrict__ p1, float* __restrict__ s1b) {
  __shared__ float lws[HID * OUT_DIM];  // 8 KB
  __shared__ float lwn[HID * OUT_DIM];  // 8 KB
  __shared__ float xt[32][HID];         // 8 KB
  const int tid = threadIdx.x;
  const int row0 = blockIdx.x * 32;
  for (int i = tid; i < HID * OUT_DIM; i += 256) {
    lws[i] = Wself[i];
    lwn[i] = Wneigh[i];
  }
  for (int i = tid; i < 32 * HID; i += 256) {
    int r = i >> 6, k = i & (HID - 1);
    int gr = row0 + r;
    xt[r][k] = (gr < N_NODES) ? h1[(size_t)gr * HID + k] : 0.f;
  }
  __syncthreads();
  const int c = tid & 31;
  const int rr = tid >> 5;  // 0..7
  float an[4] = {0.f, 0.f, 0.f, 0.f};
  float as[4] = {0.f, 0.f, 0.f, 0.f};
#pragma unroll 4
  for (int k = 0; k < HID; ++k) {
    const float wn = lwn[k * OUT_DIM + c];
    const float ws = lws[k * OUT_DIM + c];
#pragma unroll
    for (int q = 0; q < 4; ++q) {
      const float xv = xt[q * 8 + rr][k];
      an[q] += xv * wn;
      as[q] += xv * ws;
    }
  }
  const float bias = b1[c];
#pragma unroll
  for (int q = 0; q < 4; ++q) {
    const int gr = row0 + q * 8 + rr;
    if (gr < N_NODES) {
      p1[(size_t)gr * OUT_DIM + c] = an[q];
      s1b[(size_t)gr * OUT_DIM + c] = as[q] + bias;
    }
  }
}

// ---------------- Scatter layer 0: agg0[dst] += p0[src]; cnt[dst]++ ---------
__global__ __launch_bounds__(256) void scatter0(
    const int* __restrict__ src, const int* __restrict__ dst,
    const float* __restrict__ p0, float* __restrict__ agg0,
    float* __restrict__ cnt) {
  const int lane = threadIdx.x & 63;
  const int waveId = blockIdx.x * 4 + (threadIdx.x >> 6);
  const int nw = gridDim.x * 4;
  for (int e = waveId; e < N_EDGES; e += nw) {
    const int s = src[e];
    const int d = dst[e];
    const float v = p0[(size_t)s * HID + lane];
    atomicAdd(&agg0[(size_t)d * HID + lane], v);
    if (lane == 0) atomicAdd(&cnt[d], 1.0f);
  }
}

// ---------------- Scatter layer 1: agg1[dst] += p1[src] (2 edges / wave) ----
__global__ __launch_bounds__(256) void scatter1(
    const int* __restrict__ src, const int* __restrict__ dst,
    const float* __restrict__ p1, float* __restrict__ agg1) {
  const int lane = threadIdx.x & 63;
  const int half = lane >> 5;
  const int f = lane & 31;
  const int waveId = blockIdx.x * 4 + (threadIdx.x >> 6);
  const int nw = gridDim.x * 4;
  for (int e = waveId * 2 + half; e < N_EDGES; e += nw * 2) {
    const int s = src[e];
    const int d = dst[e];
    atomicAdd(&agg1[(size_t)d * OUT_DIM + f], p1[(size_t)s * OUT_DIM + f]);
  }
}

// ---------------- Combine layer 0: LN(z)*g+be, relu -> h1 (fp32) ------------
__global__ __launch_bounds__(256) void combine0(
    const float* __restrict__ s0b, const float* __restrict__ agg0,
    const float* __restrict__ cnt, const float* __restrict__ g,
    const float* __restrict__ be, float* __restrict__ h1) {
  const int lane = threadIdx.x & 63;
  const int i = blockIdx.x * 4 + (threadIdx.x >> 6);
  if (i >= N_NODES) return;
  const float inv = 1.0f / fmaxf(cnt[i], 1.0f);
  const float z = s0b[(size_t)i * HID + lane] + agg0[(size_t)i * HID + lane] * inv;
  float m = z;
#pragma unroll
  for (int mk = 1; mk < 64; mk <<= 1) m += __shfl_xor(m, mk);
  m *= (1.0f / 64.0f);
  const float dz = z - m;
  float v = dz * dz;
#pragma unroll
  for (int mk = 1; mk < 64; mk <<= 1) v += __shfl_xor(v, mk);
  v *= (1.0f / 64.0f);
  const float zn = dz * rsqrtf(v + LN_EPS) * g[lane] + be[lane];
  h1[(size_t)i * HID + lane] = fmaxf(zn, 0.0f);
}

// ---------------- Combine layer 1: LN + relu -> fp32 out (2 nodes / wave) ---
__global__ __launch_bounds__(256) void combine1(
    const float* __restrict__ s1b, const float* __restrict__ agg1,
    const float* __restrict__ cnt, const float* __restrict__ g,
    const float* __restrict__ be, float* __restrict__ out) {
  const int lane = threadIdx.x & 63;
  const int f = lane & 31;
  const int i = blockIdx.x * 8 + (threadIdx.x >> 5);
  if (i >= N_NODES) return;
  const float inv = 1.0f / fmaxf(cnt[i], 1.0f);
  const float z = s1b[(size_t)i * OUT_DIM + f] + agg1[(size_t)i * OUT_DIM + f] * inv;
  float m = z;
#pragma unroll
  for (int mk = 1; mk < 32; mk <<= 1) m += __shfl_xor(m, mk);
  m *= (1.0f / 32.0f);
  const float dz = z - m;
  float v = dz * dz;
#pragma unroll
  for (int mk = 1; mk < 32; mk <<= 1) v += __shfl_xor(v, mk);
  v *= (1.0f / 32.0f);
  float zn = dz * rsqrtf(v + LN_EPS) * g[f] + be[f];
  out[(size_t)i * OUT_DIM + f] = fmaxf(zn, 0.0f);
}

extern "C" void kernel_launch(void* const* d_in, const int* in_sizes, int n_in,
                              void* d_out, int out_size, void* d_ws, size_t ws_size,
                              hipStream_t stream) {
  const float* x       = (const float*)d_in[0];
  const int*   edges   = (const int*)d_in[1];
  const float* Wself0  = (const float*)d_in[2];
  const float* Wneigh0 = (const float*)d_in[3];
  const float* b0      = (const float*)d_in[4];
  const float* g0      = (const float*)d_in[5];
  const float* be0     = (const float*)d_in[6];
  const float* Wself1  = (const float*)d_in[7];
  const float* Wneigh1 = (const float*)d_in[8];
  const float* b1      = (const float*)d_in[9];
  const float* g1      = (const float*)d_in[10];
  const float* be1     = (const float*)d_in[11];

  // Workspace layout (≈92 MB), with region reuse:
  int* srcI = (int*)d_ws;
  int* dstI = srcI + N_EDGES;
  int* flag = dstI + N_EDGES;
  float* A = (float*)(flag + 64);          // p0, later h1          [6.4M f]
  float* B = A + (size_t)N_NODES * HID;    // s0b                   [6.4M f]
  float* C = B + (size_t)N_NODES * HID;    // agg0, later p1+s1b    [6.4M f]
  float* D = C + (size_t)N_NODES * HID;    // agg1                  [3.2M f]
  float* cnt = D + (size_t)N_NODES * OUT_DIM;  // [100k f]

  float* p0 = A;
  float* s0b = B;
  float* agg0 = C;
  float* h1 = A;                       // overwrites p0 (dead after scatter0)
  float* p1 = C;                       // overwrites agg0 (dead after combine0)
  float* s1b = C + (size_t)N_NODES * OUT_DIM;
  float* agg1 = D;

  hipMemsetAsync(agg0, 0, (size_t)N_NODES * HID * sizeof(float), stream);
  hipMemsetAsync(agg1, 0, (size_t)N_NODES * OUT_DIM * sizeof(float), stream);
  hipMemsetAsync(cnt, 0, (size_t)N_NODES * sizeof(float), stream);

  detect_edges<<<1, 256, 0, stream>>>(edges, flag);
  convert_edges<<<2048, 256, 0, stream>>>(edges, flag, srcI, dstI);

  gemm0<<<(N_NODES + 15) / 16, 256, 0, stream>>>(x, Wself0, Wneigh0, b0, p0, s0b);
  scatter0<<<4096, 256, 0, stream>>>(srcI, dstI, p0, agg0, cnt);
  combine0<<<(N_NODES + 3) / 4, 256, 0, stream>>>(s0b, agg0, cnt, g0, be0, h1);
  gemm1<<<(N_NODES + 31) / 32, 256, 0, stream>>>(h1, Wself1, Wneigh1, b1, p1, s1b);
  scatter1<<<4096, 256, 0, stream>>>(srcI, dstI, p1, agg1);
  combine1<<<(N_NODES + 7) / 8, 256, 0, stream>>>(s1b, agg1, cnt, g1, be1,
                                                  (float*)d_out);
}

// Round 3
// 499.726 us; speedup vs baseline: 1.4753x; 1.4753x over previous
//
#include <hip/hip_runtime.h>
#include <hip/hip_bf16.h>

#define N_NODES 100000
#define N_EDGES 1600000
#define IN_DIM 128
#define HID 64
#define OUT_DIM 32
#define LN_EPS 1e-5f
#define SCAN_CHUNK 1024
#define N_SCAN_BLOCKS ((N_NODES + SCAN_CHUNK - 1) / SCAN_CHUNK)  // 98

// ---------- Edge dtype detect: int64 (high words all 0) vs int32 ------------
__global__ void detect_edges(const int* __restrict__ w, int* __restrict__ flag) {
  __shared__ int any;
  if (threadIdx.x == 0) any = 0;
  __syncthreads();
  if (w[2 * threadIdx.x + 1] != 0) any = 1;  // benign race, all write 1
  __syncthreads();
  if (threadIdx.x == 0) flag[0] = any ? 0 : 1;  // 1 => int64 layout
}

__device__ __forceinline__ int loadSrc(const int* w, int i64, int e) {
  return i64 ? w[2 * e] : w[e];
}
__device__ __forceinline__ int loadDst(const int* w, int i64, int e) {
  return i64 ? w[2 * (size_t)N_EDGES + 2 * e] : w[(size_t)N_EDGES + e];
}

// ---------------- Degree histogram over dst ---------------------------------
__global__ __launch_bounds__(256) void hist(
    const int* __restrict__ w, const int* __restrict__ flag,
    int* __restrict__ deg) {
  const int i64 = flag[0];
  for (int e = blockIdx.x * 256 + threadIdx.x; e < N_EDGES;
       e += gridDim.x * 256) {
    atomicAdd(&deg[loadDst(w, i64, e)], 1);
  }
}

// ---------------- Scan stage A: per-block (1024 elems) local ex-scan --------
__global__ __launch_bounds__(256) void scanA(
    const int* __restrict__ deg, int* __restrict__ off,
    int* __restrict__ bsum) {
  __shared__ int lds[256];
  const int t = threadIdx.x;
  const int base = blockIdx.x * SCAN_CHUNK;
  int v[4];
  int s = 0;
#pragma unroll
  for (int j = 0; j < 4; ++j) {
    const int idx = base + t * 4 + j;
    v[j] = (idx < N_NODES) ? deg[idx] : 0;
    s += v[j];
  }
  lds[t] = s;
  __syncthreads();
  for (int o = 1; o < 256; o <<= 1) {
    const int val = (t >= o) ? lds[t - o] : 0;
    __syncthreads();
    lds[t] += val;
    __syncthreads();
  }
  int run = lds[t] - s;  // exclusive prefix of this thread's chunk
  if (t == 255) bsum[blockIdx.x] = lds[255];
#pragma unroll
  for (int j = 0; j < 4; ++j) {
    const int idx = base + t * 4 + j;
    if (idx < N_NODES) off[idx] = run;
    run += v[j];
  }
}

// ---------------- Scan stage B: exclusive scan of 98 block sums -------------
__global__ void scanB(const int* __restrict__ bsum, int* __restrict__ boff) {
  if (threadIdx.x == 0) {
    int s = 0;
    for (int i = 0; i < N_SCAN_BLOCKS; ++i) {
      boff[i] = s;
      s += bsum[i];
    }
  }
}

// ---------------- Scan stage C: add block offsets ---------------------------
__global__ __launch_bounds__(256) void scanC(int* __restrict__ off,
                                             const int* __restrict__ boff) {
  const int idx = blockIdx.x * 256 + threadIdx.x;
  if (idx < N_NODES) off[idx] += boff[idx / SCAN_CHUNK];
}

// ---------------- Fill: sortedSrc bucketed by dst ---------------------------
__global__ __launch_bounds__(256) void fill(
    const int* __restrict__ w, const int* __restrict__ flag,
    const int* __restrict__ off, int* __restrict__ cursor,
    int* __restrict__ sortedSrc) {
  const int i64 = flag[0];
  for (int e = blockIdx.x * 256 + threadIdx.x; e < N_EDGES;
       e += gridDim.x * 256) {
    const int d = loadDst(w, i64, e);
    const int p = atomicAdd(&cursor[d], 1);
    sortedSrc[off[d] + p] = loadSrc(w, i64, e);
  }
}

// ---------------- Layer 0 GEMM: p0 = x @ Wneigh0 ; s0b = x @ Wself0 + b0 ----
__global__ __launch_bounds__(256) void gemm0(
    const float* __restrict__ x, const float* __restrict__ Wself,
    const float* __restrict__ Wneigh, const float* __restrict__ b0,
    float* __restrict__ p0, float* __restrict__ s0b) {
  __shared__ float lws[64 * HID];   // 16 KB (k-chunk of 64)
  __shared__ float lwn[64 * HID];   // 16 KB
  __shared__ float xt[16][IN_DIM];  // 8 KB
  const int tid = threadIdx.x;
  const int row0 = blockIdx.x * 16;
  for (int i = tid; i < 16 * IN_DIM; i += 256) {
    int r = i >> 7, k = i & (IN_DIM - 1);
    int gr = row0 + r;
    xt[r][k] = (gr < N_NODES) ? x[(size_t)gr * IN_DIM + k] : 0.f;
  }
  const int c = tid & 63;
  const int rr = tid >> 6;  // 0..3
  float an[4] = {0.f, 0.f, 0.f, 0.f};
  float as[4] = {0.f, 0.f, 0.f, 0.f};
  for (int kc = 0; kc < 2; ++kc) {
    __syncthreads();
    for (int i = tid; i < 64 * HID; i += 256) {
      lws[i] = Wself[kc * 64 * HID + i];
      lwn[i] = Wneigh[kc * 64 * HID + i];
    }
    __syncthreads();
#pragma unroll 4
    for (int k = 0; k < 64; ++k) {
      const float wn = lwn[k * HID + c];
      const float ws = lws[k * HID + c];
#pragma unroll
      for (int q = 0; q < 4; ++q) {
        const float xv = xt[q * 4 + rr][kc * 64 + k];
        an[q] += xv * wn;
        as[q] += xv * ws;
      }
    }
  }
  const float bias = b0[c];
#pragma unroll
  for (int q = 0; q < 4; ++q) {
    const int gr = row0 + q * 4 + rr;
    if (gr < N_NODES) {
      p0[(size_t)gr * HID + c] = an[q];
      s0b[(size_t)gr * HID + c] = as[q] + bias;
    }
  }
}

// ---------------- Layer 1 GEMM: p1 = h1 @ Wneigh1 ; s1b = h1 @ Wself1 + b1 --
__global__ __launch_bounds__(256) void gemm1(
    const float* __restrict__ h1, const float* __restrict__ Wself,
    const float* __restrict__ Wneigh, const float* __restrict__ b1,
    float* __restrict__ p1, float* __restrict__ s1b) {
  __shared__ float lws[HID * OUT_DIM];  // 8 KB
  __shared__ float lwn[HID * OUT_DIM];  // 8 KB
  __shared__ float xt[32][HID];         // 8 KB
  const int tid = threadIdx.x;
  const int row0 = blockIdx.x * 32;
  for (int i = tid; i < HID * OUT_DIM; i += 256) {
    lws[i] = Wself[i];
    lwn[i] = Wneigh[i];
  }
  for (int i = tid; i < 32 * HID; i += 256) {
    int r = i >> 6, k = i & (HID - 1);
    int gr = row0 + r;
    xt[r][k] = (gr < N_NODES) ? h1[(size_t)gr * HID + k] : 0.f;
  }
  __syncthreads();
  const int c = tid & 31;
  const int rr = tid >> 5;  // 0..7
  float an[4] = {0.f, 0.f, 0.f, 0.f};
  float as[4] = {0.f, 0.f, 0.f, 0.f};
#pragma unroll 4
  for (int k = 0; k < HID; ++k) {
    const float wn = lwn[k * OUT_DIM + c];
    const float ws = lws[k * OUT_DIM + c];
#pragma unroll
    for (int q = 0; q < 4; ++q) {
      const float xv = xt[q * 8 + rr][k];
      an[q] += xv * wn;
      as[q] += xv * ws;
    }
  }
  const float bias = b1[c];
#pragma unroll
  for (int q = 0; q < 4; ++q) {
    const int gr = row0 + q * 8 + rr;
    if (gr < N_NODES) {
      p1[(size_t)gr * OUT_DIM + c] = an[q];
      s1b[(size_t)gr * OUT_DIM + c] = as[q] + bias;
    }
  }
}

// ------- Fused layer-0 aggregate (gather) + mean + LN + ReLU -> h1 ----------
__global__ __launch_bounds__(256) void aggc0(
    const int* __restrict__ sortedSrc, const int* __restrict__ off,
    const int* __restrict__ deg, const float* __restrict__ p0,
    const float* __restrict__ s0b, const float* __restrict__ g,
    const float* __restrict__ be, float* __restrict__ h1) {
  const int lane = threadIdx.x & 63;
  const int i = blockIdx.x * 4 + (threadIdx.x >> 6);
  if (i >= N_NODES) return;
  const int st = off[i];
  const int dg = deg[i];
  float acc = 0.f;
  int e = st;
  for (; e + 1 < st + dg; e += 2) {
    const int s0 = sortedSrc[e];
    const int s1 = sortedSrc[e + 1];
    const float a = p0[(size_t)s0 * HID + lane];
    const float b = p0[(size_t)s1 * HID + lane];
    acc += a;
    acc += b;
  }
  if (e < st + dg) acc += p0[(size_t)sortedSrc[e] * HID + lane];
  const float inv = 1.0f / fmaxf((float)dg, 1.0f);
  const float z = s0b[(size_t)i * HID + lane] + acc * inv;
  float m = z;
#pragma unroll
  for (int mk = 1; mk < 64; mk <<= 1) m += __shfl_xor(m, mk);
  m *= (1.0f / 64.0f);
  const float dz = z - m;
  float v = dz * dz;
#pragma unroll
  for (int mk = 1; mk < 64; mk <<= 1) v += __shfl_xor(v, mk);
  v *= (1.0f / 64.0f);
  const float zn = dz * rsqrtf(v + LN_EPS) * g[lane] + be[lane];
  h1[(size_t)i * HID + lane] = fmaxf(zn, 0.0f);
}

// ------- Fused layer-1 aggregate + mean + LN + ReLU -> out ------------------
// One node per wave; lanes split into 2 halves, each gathers alternate edges.
__global__ __launch_bounds__(256) void aggc1(
    const int* __restrict__ sortedSrc, const int* __restrict__ off,
    const int* __restrict__ deg, const float* __restrict__ p1,
    const float* __restrict__ s1b, const float* __restrict__ g,
    const float* __restrict__ be, float* __restrict__ out) {
  const int lane = threadIdx.x & 63;
  const int half = lane >> 5;
  const int f = lane & 31;
  const int i = blockIdx.x * 4 + (threadIdx.x >> 6);
  if (i >= N_NODES) return;
  const int st = off[i];
  const int dg = deg[i];
  float acc = 0.f;
  for (int e = st + half; e < st + dg; e += 2) {
    acc += p1[(size_t)sortedSrc[e] * OUT_DIM + f];
  }
  acc += __shfl_xor(acc, 32);  // both halves now hold full sum
  const float inv = 1.0f / fmaxf((float)dg, 1.0f);
  const float z = s1b[(size_t)i * OUT_DIM + f] + acc * inv;
  float m = z;
#pragma unroll
  for (int mk = 1; mk < 32; mk <<= 1) m += __shfl_xor(m, mk);
  m *= (1.0f / 32.0f);
  const float dz = z - m;
  float v = dz * dz;
#pragma unroll
  for (int mk = 1; mk < 32; mk <<= 1) v += __shfl_xor(v, mk);
  v *= (1.0f / 32.0f);
  float zn = dz * rsqrtf(v + LN_EPS) * g[f] + be[f];
  if (half == 0) out[(size_t)i * OUT_DIM + f] = fmaxf(zn, 0.0f);
}

extern "C" void kernel_launch(void* const* d_in, const int* in_sizes, int n_in,
                              void* d_out, int out_size, void* d_ws, size_t ws_size,
                              hipStream_t stream) {
  const float* x       = (const float*)d_in[0];
  const int*   edges   = (const int*)d_in[1];
  const float* Wself0  = (const float*)d_in[2];
  const float* Wneigh0 = (const float*)d_in[3];
  const float* b0      = (const float*)d_in[4];
  const float* g0      = (const float*)d_in[5];
  const float* be0     = (const float*)d_in[6];
  const float* Wself1  = (const float*)d_in[7];
  const float* Wneigh1 = (const float*)d_in[8];
  const float* b1      = (const float*)d_in[9];
  const float* g1      = (const float*)d_in[10];
  const float* be1     = (const float*)d_in[11];

  // Workspace (~85 MB): flag | sortedSrc | off | deg | cursor | bsum | boff |
  //                     p0 (later p1+s1b) | s0b | h1
  int* flag      = (int*)d_ws;
  int* sortedSrc = flag + 64;
  int* off       = sortedSrc + N_EDGES;
  int* deg       = off + N_NODES;
  int* cursor    = deg + N_NODES;
  int* bsum      = cursor + N_NODES;
  int* boff      = bsum + 128;
  float* p0      = (float*)(boff + 128);
  float* s0b     = p0 + (size_t)N_NODES * HID;
  float* h1      = s0b + (size_t)N_NODES * HID;
  float* p1      = p0;                              // overlay (p0 dead)
  float* s1b     = p0 + (size_t)N_NODES * OUT_DIM;  // overlay

  hipMemsetAsync(deg, 0, N_NODES * sizeof(int), stream);
  hipMemsetAsync(cursor, 0, N_NODES * sizeof(int), stream);

  detect_edges<<<1, 256, 0, stream>>>(edges, flag);
  hist<<<2048, 256, 0, stream>>>(edges, flag, deg);
  scanA<<<N_SCAN_BLOCKS, 256, 0, stream>>>(deg, off, bsum);
  scanB<<<1, 64, 0, stream>>>(bsum, boff);
  scanC<<<(N_NODES + 255) / 256, 256, 0, stream>>>(off, boff);
  fill<<<2048, 256, 0, stream>>>(edges, flag, off, cursor, sortedSrc);

  gemm0<<<(N_NODES + 15) / 16, 256, 0, stream>>>(x, Wself0, Wneigh0, b0, p0, s0b);
  aggc0<<<(N_NODES + 3) / 4, 256, 0, stream>>>(sortedSrc, off, deg, p0, s0b,
                                               g0, be0, h1);
  gemm1<<<(N_NODES + 31) / 32, 256, 0, stream>>>(h1, Wself1, Wneigh1, b1, p1, s1b);
  aggc1<<<(N_NODES + 3) / 4, 256, 0, stream>>>(sortedSrc, off, deg, p1, s1b,
                                               g1, be1, (float*)d_out);
}

// Round 4
// 349.341 us; speedup vs baseline: 2.1103x; 1.4305x over previous
//
#include <hip/hip_runtime.h>
#include <hip/hip_bf16.h>

#define N_NODES 100000
#define N_EDGES 1600000
#define IN_DIM 128
#define HID 64
#define OUT_DIM 32
#define LN_EPS 1e-5f
#define SCAN_CHUNK 1024
#define N_SCAN_BLOCKS ((N_NODES + SCAN_CHUNK - 1) / SCAN_CHUNK)  // 98

// ---------- Edge dtype detect: int64 (high words all 0) vs int32 ------------
__global__ void detect_edges(const int* __restrict__ w, int* __restrict__ flag) {
  __shared__ int any;
  if (threadIdx.x == 0) any = 0;
  __syncthreads();
  if (w[2 * threadIdx.x + 1] != 0) any = 1;  // benign race, all write 1
  __syncthreads();
  if (threadIdx.x == 0) flag[0] = any ? 0 : 1;  // 1 => int64 layout
}

// ---------------- Histogram over dst + per-edge position --------------------
// 2 edges per thread via vector loads; pos[e] = arrival order within bucket.
__global__ __launch_bounds__(256) void hist(
    const int* __restrict__ w, const int* __restrict__ flag,
    int* __restrict__ deg, int* __restrict__ pos) {
  const int i64 = flag[0];
  const int npairs = N_EDGES / 2;
  for (int p = blockIdx.x * 256 + threadIdx.x; p < npairs;
       p += gridDim.x * 256) {
    int d0, d1;
    if (i64) {
      const int4 v = *(const int4*)(w + 2 * (size_t)N_EDGES + 4 * (size_t)p);
      d0 = v.x;
      d1 = v.z;
    } else {
      const int2 v = *(const int2*)(w + (size_t)N_EDGES + 2 * (size_t)p);
      d0 = v.x;
      d1 = v.y;
    }
    const int p0 = atomicAdd(&deg[d0], 1);
    const int p1 = atomicAdd(&deg[d1], 1);
    pos[2 * p] = p0;
    pos[2 * p + 1] = p1;
  }
}

// ---------------- Scan stage A: per-block (1024 elems) local ex-scan --------
__global__ __launch_bounds__(256) void scanA(
    const int* __restrict__ deg, int* __restrict__ off,
    int* __restrict__ bsum) {
  __shared__ int lds[256];
  const int t = threadIdx.x;
  const int base = blockIdx.x * SCAN_CHUNK;
  int v[4];
  int s = 0;
#pragma unroll
  for (int j = 0; j < 4; ++j) {
    const int idx = base + t * 4 + j;
    v[j] = (idx < N_NODES) ? deg[idx] : 0;
    s += v[j];
  }
  lds[t] = s;
  __syncthreads();
  for (int o = 1; o < 256; o <<= 1) {
    const int val = (t >= o) ? lds[t - o] : 0;
    __syncthreads();
    lds[t] += val;
    __syncthreads();
  }
  int run = lds[t] - s;  // exclusive prefix of this thread's chunk
  if (t == 255) bsum[blockIdx.x] = lds[255];
#pragma unroll
  for (int j = 0; j < 4; ++j) {
    const int idx = base + t * 4 + j;
    if (idx < N_NODES) off[idx] = run;
    run += v[j];
  }
}

// ---------------- Scan stage B: 1-wave shuffle scan of 98 block sums --------
__global__ void scanB(const int* __restrict__ bsum, int* __restrict__ boff) {
  const int l = threadIdx.x;  // 64 lanes, 2 elems each
  const int i0 = 2 * l, i1 = 2 * l + 1;
  const int v0 = (i0 < N_SCAN_BLOCKS) ? bsum[i0] : 0;
  const int v1 = (i1 < N_SCAN_BLOCKS) ? bsum[i1] : 0;
  int s = v0 + v1;
#pragma unroll
  for (int o = 1; o < 64; o <<= 1) {
    const int t = __shfl_up(s, o);
    if (l >= o) s += t;
  }
  const int excl = s - (v0 + v1);
  if (i0 < N_SCAN_BLOCKS) boff[i0] = excl;
  if (i1 < N_SCAN_BLOCKS) boff[i1] = excl + v0;
}

// ---------------- Scan stage C: add block offsets ---------------------------
__global__ __launch_bounds__(256) void scanC(int* __restrict__ off,
                                             const int* __restrict__ boff) {
  const int idx = blockIdx.x * 256 + threadIdx.x;
  if (idx < N_NODES) off[idx] += boff[idx / SCAN_CHUNK];
}

// ---------------- Fill: sortedSrc[off[d]+pos[e]] = src[e] (no atomics) ------
__global__ __launch_bounds__(256) void fill(
    const int* __restrict__ w, const int* __restrict__ flag,
    const int* __restrict__ off, const int* __restrict__ pos,
    int* __restrict__ sortedSrc) {
  const int i64 = flag[0];
  const int npairs = N_EDGES / 2;
  for (int p = blockIdx.x * 256 + threadIdx.x; p < npairs;
       p += gridDim.x * 256) {
    int s0, s1, d0, d1;
    if (i64) {
      const int4 vs = *(const int4*)(w + 4 * (size_t)p);
      const int4 vd = *(const int4*)(w + 2 * (size_t)N_EDGES + 4 * (size_t)p);
      s0 = vs.x; s1 = vs.z;
      d0 = vd.x; d1 = vd.z;
    } else {
      const int2 vs = *(const int2*)(w + 2 * (size_t)p);
      const int2 vd = *(const int2*)(w + (size_t)N_EDGES + 2 * (size_t)p);
      s0 = vs.x; s1 = vs.y;
      d0 = vd.x; d1 = vd.y;
    }
    const int2 pp = *(const int2*)(pos + 2 * (size_t)p);
    sortedSrc[off[d0] + pp.x] = s0;
    sortedSrc[off[d1] + pp.y] = s1;
  }
}

// ---------------- Layer 0 GEMM: p0 = x @ Wneigh0 ; s0b = x @ Wself0 + b0 ----
__global__ __launch_bounds__(256) void gemm0(
    const float* __restrict__ x, const float* __restrict__ Wself,
    const float* __restrict__ Wneigh, const float* __restrict__ b0,
    float* __restrict__ p0, float* __restrict__ s0b) {
  __shared__ float lws[64 * HID];   // 16 KB (k-chunk of 64)
  __shared__ float lwn[64 * HID];   // 16 KB
  __shared__ float xt[16][IN_DIM];  // 8 KB
  const int tid = threadIdx.x;
  const int row0 = blockIdx.x * 16;
  for (int i = tid; i < 16 * IN_DIM; i += 256) {
    int r = i >> 7, k = i & (IN_DIM - 1);
    int gr = row0 + r;
    xt[r][k] = (gr < N_NODES) ? x[(size_t)gr * IN_DIM + k] : 0.f;
  }
  const int c = tid & 63;
  const int rr = tid >> 6;  // 0..3
  float an[4] = {0.f, 0.f, 0.f, 0.f};
  float as[4] = {0.f, 0.f, 0.f, 0.f};
  for (int kc = 0; kc < 2; ++kc) {
    __syncthreads();
    for (int i = tid; i < 64 * HID; i += 256) {
      lws[i] = Wself[kc * 64 * HID + i];
      lwn[i] = Wneigh[kc * 64 * HID + i];
    }
    __syncthreads();
#pragma unroll 4
    for (int k = 0; k < 64; ++k) {
      const float wn = lwn[k * HID + c];
      const float ws = lws[k * HID + c];
#pragma unroll
      for (int q = 0; q < 4; ++q) {
        const float xv = xt[q * 4 + rr][kc * 64 + k];
        an[q] += xv * wn;
        as[q] += xv * ws;
      }
    }
  }
  const float bias = b0[c];
#pragma unroll
  for (int q = 0; q < 4; ++q) {
    const int gr = row0 + q * 4 + rr;
    if (gr < N_NODES) {
      p0[(size_t)gr * HID + c] = an[q];
      s0b[(size_t)gr * HID + c] = as[q] + bias;
    }
  }
}

// ---------------- Layer 1 GEMM: p1 = h1 @ Wneigh1 ; s1b = h1 @ Wself1 + b1 --
__global__ __launch_bounds__(256) void gemm1(
    const float* __restrict__ h1, const float* __restrict__ Wself,
    const float* __restrict__ Wneigh, const float* __restrict__ b1,
    float* __restrict__ p1, float* __restrict__ s1b) {
  __shared__ float lws[HID * OUT_DIM];  // 8 KB
  __shared__ float lwn[HID * OUT_DIM];  // 8 KB
  __shared__ float xt[32][HID];         // 8 KB
  const int tid = threadIdx.x;
  const int row0 = blockIdx.x * 32;
  for (int i = tid; i < HID * OUT_DIM; i += 256) {
    lws[i] = Wself[i];
    lwn[i] = Wneigh[i];
  }
  for (int i = tid; i < 32 * HID; i += 256) {
    int r = i >> 6, k = i & (HID - 1);
    int gr = row0 + r;
    xt[r][k] = (gr < N_NODES) ? h1[(size_t)gr * HID + k] : 0.f;
  }
  __syncthreads();
  const int c = tid & 31;
  const int rr = tid >> 5;  // 0..7
  float an[4] = {0.f, 0.f, 0.f, 0.f};
  float as[4] = {0.f, 0.f, 0.f, 0.f};
#pragma unroll 4
  for (int k = 0; k < HID; ++k) {
    const float wn = lwn[k * OUT_DIM + c];
    const float ws = lws[k * OUT_DIM + c];
#pragma unroll
    for (int q = 0; q < 4; ++q) {
      const float xv = xt[q * 8 + rr][k];
      an[q] += xv * wn;
      as[q] += xv * ws;
    }
  }
  const float bias = b1[c];
#pragma unroll
  for (int q = 0; q < 4; ++q) {
    const int gr = row0 + q * 8 + rr;
    if (gr < N_NODES) {
      p1[(size_t)gr * OUT_DIM + c] = an[q];
      s1b[(size_t)gr * OUT_DIM + c] = as[q] + bias;
    }
  }
}

// ------- Fused layer-0 aggregate (gather) + mean + LN + ReLU -> h1 ----------
// One node per wave. Lane-parallel index preload + shuffle broadcast;
// 4 independent accumulators for memory-level parallelism.
__global__ __launch_bounds__(256) void aggc0(
    const int* __restrict__ sortedSrc, const int* __restrict__ off,
    const int* __restrict__ deg, const float* __restrict__ p0,
    const float* __restrict__ s0b, const float* __restrict__ g,
    const float* __restrict__ be, float* __restrict__ h1) {
  const int lane = threadIdx.x & 63;
  const int i = blockIdx.x * 4 + (threadIdx.x >> 6);
  if (i >= N_NODES) return;
  const int st = off[i];
  const int dg = deg[i];
  float a0 = 0.f, a1 = 0.f, a2 = 0.f, a3 = 0.f;
  for (int base = 0; base < dg; base += 64) {
    const int cnt = min(64, dg - base);
    const int idx = (lane < cnt) ? sortedSrc[st + base + lane] : 0;
    int j = 0;
    for (; j + 3 < cnt; j += 4) {
      const int s0 = __shfl(idx, j);
      const int s1 = __shfl(idx, j + 1);
      const int s2 = __shfl(idx, j + 2);
      const int s3 = __shfl(idx, j + 3);
      a0 += p0[(size_t)s0 * HID + lane];
      a1 += p0[(size_t)s1 * HID + lane];
      a2 += p0[(size_t)s2 * HID + lane];
      a3 += p0[(size_t)s3 * HID + lane];
    }
    for (; j < cnt; ++j) a0 += p0[(size_t)__shfl(idx, j) * HID + lane];
  }
  const float acc = (a0 + a1) + (a2 + a3);
  const float inv = 1.0f / fmaxf((float)dg, 1.0f);
  const float z = s0b[(size_t)i * HID + lane] + acc * inv;
  float m = z;
#pragma unroll
  for (int mk = 1; mk < 64; mk <<= 1) m += __shfl_xor(m, mk);
  m *= (1.0f / 64.0f);
  const float dz = z - m;
  float v = dz * dz;
#pragma unroll
  for (int mk = 1; mk < 64; mk <<= 1) v += __shfl_xor(v, mk);
  v *= (1.0f / 64.0f);
  const float zn = dz * rsqrtf(v + LN_EPS) * g[lane] + be[lane];
  h1[(size_t)i * HID + lane] = fmaxf(zn, 0.0f);
}

// ------- Fused layer-1 aggregate + mean + LN + ReLU -> out ------------------
// One node per wave; two 32-lane halves each sum alternate edges.
// Uniform predicated loop keeps the wave convergent around shuffles.
__global__ __launch_bounds__(256) void aggc1(
    const int* __restrict__ sortedSrc, const int* __restrict__ off,
    const int* __restrict__ deg, const float* __restrict__ p1,
    const float* __restrict__ s1b, const float* __restrict__ g,
    const float* __restrict__ be, float* __restrict__ out) {
  const int lane = threadIdx.x & 63;
  const int half = lane >> 5;
  const int f = lane & 31;
  const int i = blockIdx.x * 4 + (threadIdx.x >> 6);
  if (i >= N_NODES) return;
  const int st = off[i];
  const int dg = deg[i];
  float a0 = 0.f, a1 = 0.f, a2 = 0.f, a3 = 0.f;
  for (int base = 0; base < dg; base += 64) {
    const int cnt = min(64, dg - base);
    const int idx = (lane < cnt) ? sortedSrc[st + base + lane] : 0;
    for (int j = 0; j < cnt; j += 8) {
      const int j0 = j + half, j1 = j + 2 + half, j2 = j + 4 + half,
                j3 = j + 6 + half;
      const int s0 = __shfl(idx, j0 & 63);
      const int s1 = __shfl(idx, j1 & 63);
      const int s2 = __shfl(idx, j2 & 63);
      const int s3 = __shfl(idx, j3 & 63);
      if (j0 < cnt) a0 += p1[(size_t)s0 * OUT_DIM + f];
      if (j1 < cnt) a1 += p1[(size_t)s1 * OUT_DIM + f];
      if (j2 < cnt) a2 += p1[(size_t)s2 * OUT_DIM + f];
      if (j3 < cnt) a3 += p1[(size_t)s3 * OUT_DIM + f];
    }
  }
  float acc = (a0 + a1) + (a2 + a3);
  acc += __shfl_xor(acc, 32);  // both halves now hold full sum
  const float inv = 1.0f / fmaxf((float)dg, 1.0f);
  const float z = s1b[(size_t)i * OUT_DIM + f] + acc * inv;
  float m = z;
#pragma unroll
  for (int mk = 1; mk < 32; mk <<= 1) m += __shfl_xor(m, mk);
  m *= (1.0f / 32.0f);
  const float dz = z - m;
  float v = dz * dz;
#pragma unroll
  for (int mk = 1; mk < 32; mk <<= 1) v += __shfl_xor(v, mk);
  v *= (1.0f / 32.0f);
  float zn = dz * rsqrtf(v + LN_EPS) * g[f] + be[f];
  if (half == 0) out[(size_t)i * OUT_DIM + f] = fmaxf(zn, 0.0f);
}

extern "C" void kernel_launch(void* const* d_in, const int* in_sizes, int n_in,
                              void* d_out, int out_size, void* d_ws, size_t ws_size,
                              hipStream_t stream) {
  const float* x       = (const float*)d_in[0];
  const int*   edges   = (const int*)d_in[1];
  const float* Wself0  = (const float*)d_in[2];
  const float* Wneigh0 = (const float*)d_in[3];
  const float* b0      = (const float*)d_in[4];
  const float* g0      = (const float*)d_in[5];
  const float* be0     = (const float*)d_in[6];
  const float* Wself1  = (const float*)d_in[7];
  const float* Wneigh1 = (const float*)d_in[8];
  const float* b1      = (const float*)d_in[9];
  const float* g1      = (const float*)d_in[10];
  const float* be1     = (const float*)d_in[11];

  // Workspace (~90 MB): flag | sortedSrc | pos | off | deg | bsum | boff |
  //                     p0 (later p1+s1b) | s0b | h1
  int* flag      = (int*)d_ws;
  int* sortedSrc = flag + 64;
  int* pos       = sortedSrc + N_EDGES;
  int* off       = pos + N_EDGES;
  int* deg       = off + N_NODES;
  int* bsum      = deg + N_NODES;
  int* boff      = bsum + 128;
  float* p0      = (float*)(boff + 128);
  float* s0b     = p0 + (size_t)N_NODES * HID;
  float* h1      = s0b + (size_t)N_NODES * HID;
  float* p1      = p0;                              // overlay (p0 dead)
  float* s1b     = p0 + (size_t)N_NODES * OUT_DIM;  // overlay

  hipMemsetAsync(deg, 0, N_NODES * sizeof(int), stream);

  detect_edges<<<1, 256, 0, stream>>>(edges, flag);
  hist<<<1024, 256, 0, stream>>>(edges, flag, deg, pos);
  scanA<<<N_SCAN_BLOCKS, 256, 0, stream>>>(deg, off, bsum);
  scanB<<<1, 64, 0, stream>>>(bsum, boff);
  scanC<<<(N_NODES + 255) / 256, 256, 0, stream>>>(off, boff);
  fill<<<1024, 256, 0, stream>>>(edges, flag, off, pos, sortedSrc);

  gemm0<<<(N_NODES + 15) / 16, 256, 0, stream>>>(x, Wself0, Wneigh0, b0, p0, s0b);
  aggc0<<<(N_NODES + 3) / 4, 256, 0, stream>>>(sortedSrc, off, deg, p0, s0b,
                                               g0, be0, h1);
  gemm1<<<(N_NODES + 31) / 32, 256, 0, stream>>>(h1, Wself1, Wneigh1, b1, p1, s1b);
  aggc1<<<(N_NODES + 3) / 4, 256, 0, stream>>>(sortedSrc, off, deg, p1, s1b,
                                               g1, be1, (float*)d_out);
}

// Round 5
// 284.669 us; speedup vs baseline: 2.5898x; 1.2272x over previous
//
#include <hip/hip_runtime.h>
#include <hip/hip_bf16.h>

#define N_NODES 100000
#define N_EDGES 1600000
#define IN_DIM 128
#define HID 64
#define OUT_DIM 32
#define LN_EPS 1e-5f
#define SCAN_CHUNK 1024
#define N_SCAN_BLOCKS ((N_NODES + SCAN_CHUNK - 1) / SCAN_CHUNK)  // 98

typedef __attribute__((ext_vector_type(8))) short short8;
typedef __attribute__((ext_vector_type(4))) float f32x4;

__device__ __forceinline__ float uf(unsigned short u) {
  return __uint_as_float(((unsigned int)u) << 16);
}
__device__ __forceinline__ unsigned short bf16rne(float f) {
  unsigned int u = __float_as_uint(f);
  unsigned int r = u + 0x7fffu + ((u >> 16) & 1u);
  return (unsigned short)(r >> 16);
}

// ---------- Edge dtype detect: int64 (high words all 0) vs int32 ------------
__global__ void detect_edges(const int* __restrict__ w, int* __restrict__ flag) {
  __shared__ int any;
  if (threadIdx.x == 0) any = 0;
  __syncthreads();
  if (w[2 * threadIdx.x + 1] != 0) any = 1;  // benign race, all write 1
  __syncthreads();
  if (threadIdx.x == 0) flag[0] = any ? 0 : 1;  // 1 => int64 layout
}

// ---------- Weight split: B0 [128n][128k] hi/lo, B1 [64n][64k] hi/lo --------
// B0: n<64 -> Wneigh0 (out cols -> p0), n>=64 -> Wself0 (-> s0b). Col-major.
__global__ __launch_bounds__(256) void convW(
    const float* __restrict__ Wn0, const float* __restrict__ Ws0,
    const float* __restrict__ Wn1, const float* __restrict__ Ws1,
    unsigned short* __restrict__ B0h, unsigned short* __restrict__ B0l,
    unsigned short* __restrict__ B1h, unsigned short* __restrict__ B1l) {
  const int i = blockIdx.x * 256 + threadIdx.x;
  if (i < 128 * 128) {
    const int n = i >> 7, k = i & 127;
    const float w = (n < 64) ? Wn0[k * 64 + n] : Ws0[k * 64 + (n - 64)];
    const unsigned short hi = bf16rne(w);
    B0h[i] = hi;
    B0l[i] = bf16rne(w - uf(hi));
  } else if (i < 128 * 128 + 64 * 64) {
    const int j = i - 128 * 128;
    const int n = j >> 6, k = j & 63;
    const float w = (n < 32) ? Wn1[k * 32 + n] : Ws1[k * 32 + (n - 32)];
    const unsigned short hi = bf16rne(w);
    B1h[j] = hi;
    B1l[j] = bf16rne(w - uf(hi));
  }
}

// ---------------- Histogram over dst + per-edge position --------------------
__global__ __launch_bounds__(256) void hist(
    const int* __restrict__ w, const int* __restrict__ flag,
    int* __restrict__ deg, int* __restrict__ pos) {
  const int i64 = flag[0];
  const int npairs = N_EDGES / 2;
  for (int p = blockIdx.x * 256 + threadIdx.x; p < npairs;
       p += gridDim.x * 256) {
    int d0, d1;
    if (i64) {
      const int4 v = *(const int4*)(w + 2 * (size_t)N_EDGES + 4 * (size_t)p);
      d0 = v.x;
      d1 = v.z;
    } else {
      const int2 v = *(const int2*)(w + (size_t)N_EDGES + 2 * (size_t)p);
      d0 = v.x;
      d1 = v.y;
    }
    const int p0 = atomicAdd(&deg[d0], 1);
    const int p1 = atomicAdd(&deg[d1], 1);
    pos[2 * p] = p0;
    pos[2 * p + 1] = p1;
  }
}

// ---------------- Scan stage A: per-block (1024 elems) local ex-scan --------
__global__ __launch_bounds__(256) void scanA(
    const int* __restrict__ deg, int* __restrict__ off,
    int* __restrict__ bsum) {
  __shared__ int lds[256];
  const int t = threadIdx.x;
  const int base = blockIdx.x * SCAN_CHUNK;
  int v[4];
  int s = 0;
#pragma unroll
  for (int j = 0; j < 4; ++j) {
    const int idx = base + t * 4 + j;
    v[j] = (idx < N_NODES) ? deg[idx] : 0;
    s += v[j];
  }
  lds[t] = s;
  __syncthreads();
  for (int o = 1; o < 256; o <<= 1) {
    const int val = (t >= o) ? lds[t - o] : 0;
    __syncthreads();
    lds[t] += val;
    __syncthreads();
  }
  int run = lds[t] - s;
  if (t == 255) bsum[blockIdx.x] = lds[255];
#pragma unroll
  for (int j = 0; j < 4; ++j) {
    const int idx = base + t * 4 + j;
    if (idx < N_NODES) off[idx] = run;
    run += v[j];
  }
}

// ---------------- Scan stage B: 1-wave shuffle scan of 98 block sums --------
__global__ void scanB(const int* __restrict__ bsum, int* __restrict__ boff) {
  const int l = threadIdx.x;
  const int i0 = 2 * l, i1 = 2 * l + 1;
  const int v0 = (i0 < N_SCAN_BLOCKS) ? bsum[i0] : 0;
  const int v1 = (i1 < N_SCAN_BLOCKS) ? bsum[i1] : 0;
  int s = v0 + v1;
#pragma unroll
  for (int o = 1; o < 64; o <<= 1) {
    const int t = __shfl_up(s, o);
    if (l >= o) s += t;
  }
  const int excl = s - (v0 + v1);
  if (i0 < N_SCAN_BLOCKS) boff[i0] = excl;
  if (i1 < N_SCAN_BLOCKS) boff[i1] = excl + v0;
}

// ---------------- Scan stage C: add block offsets ---------------------------
__global__ __launch_bounds__(256) void scanC(int* __restrict__ off,
                                             const int* __restrict__ boff) {
  const int idx = blockIdx.x * 256 + threadIdx.x;
  if (idx < N_NODES) off[idx] += boff[idx / SCAN_CHUNK];
}

// ---------------- Fill: sortedSrc[off[d]+pos[e]] = src[e] (no atomics) ------
__global__ __launch_bounds__(256) void fill(
    const int* __restrict__ w, const int* __restrict__ flag,
    const int* __restrict__ off, const int* __restrict__ pos,
    int* __restrict__ sortedSrc) {
  const int i64 = flag[0];
  const int npairs = N_EDGES / 2;
  for (int p = blockIdx.x * 256 + threadIdx.x; p < npairs;
       p += gridDim.x * 256) {
    int s0, s1, d0, d1;
    if (i64) {
      const int4 vs = *(const int4*)(w + 4 * (size_t)p);
      const int4 vd = *(const int4*)(w + 2 * (size_t)N_EDGES + 4 * (size_t)p);
      s0 = vs.x; s1 = vs.z;
      d0 = vd.x; d1 = vd.z;
    } else {
      const int2 vs = *(const int2*)(w + 2 * (size_t)p);
      const int2 vd = *(const int2*)(w + (size_t)N_EDGES + 2 * (size_t)p);
      s0 = vs.x; s1 = vs.y;
      d0 = vd.x; d1 = vd.y;
    }
    const int2 pp = *(const int2*)(pos + 2 * (size_t)p);
    sortedSrc[off[d0] + pp.x] = s0;
    sortedSrc[off[d1] + pp.y] = s1;
  }
}

// ------- Layer 0 MFMA GEMM: [p0 | s0b] = x @ [Wneigh0 | Wself0] (+b0) -------
// 4 waves/block, 16 rows/wave, 64 rows/block. Split-bf16 3-pass for accuracy.
// B in LDS col-major [n][k] bf16 with XOR-swizzle; A frags straight from HBM.
__global__ __launch_bounds__(256) void gemm0(
    const float* __restrict__ x, const unsigned short* __restrict__ B0h,
    const unsigned short* __restrict__ B0l, const float* __restrict__ b0,
    unsigned short* __restrict__ p0u, float* __restrict__ s0b) {
  __shared__ unsigned short lbh[128 * 128];  // 32 KB
  __shared__ unsigned short lbl[128 * 128];  // 32 KB
  const int tid = threadIdx.x;
  {
    const uint4* gh = (const uint4*)B0h;
    const uint4* gl = (const uint4*)B0l;
    for (int i = tid; i < 2048; i += 256) {
      const int o = i << 4;
      const int sw = o ^ (((o >> 8) & 7) << 4);
      *(uint4*)((char*)lbh + sw) = gh[i];
      *(uint4*)((char*)lbl + sw) = gl[i];
    }
  }
  __syncthreads();
  const int lane = tid & 63;
  const int wave = tid >> 6;
  const int rowbase = blockIdx.x * 64 + wave * 16;
  const int arow = rowbase + (lane & 15);
  const int rclamp = (arow < N_NODES) ? arow : 0;
  const int ko = (lane >> 4) << 3;  // 0,8,16,24

  f32x4 acc[8];
#pragma unroll
  for (int ct = 0; ct < 8; ++ct) acc[ct] = (f32x4){0.f, 0.f, 0.f, 0.f};

  for (int ks = 0; ks < 4; ++ks) {
    float av[8];
    const float* ax = x + (size_t)rclamp * IN_DIM + ks * 32 + ko;
    *(float4*)&av[0] = *(const float4*)ax;
    *(float4*)&av[4] = *(const float4*)(ax + 4);
    short8 ah, al;
#pragma unroll
    for (int j = 0; j < 8; ++j) {
      const unsigned short hi = bf16rne(av[j]);
      ah[j] = (short)hi;
      al[j] = (short)bf16rne(av[j] - uf(hi));
    }
    const int kb = ks * 64 + (ko << 1);
#pragma unroll
    for (int ct = 0; ct < 8; ++ct) {
      const int n = ct * 16 + (lane & 15);
      const int boff = (n << 8) + kb;
      const int sb = boff ^ (((boff >> 8) & 7) << 4);
      const short8 bh = *(const short8*)((const char*)lbh + sb);
      const short8 bl = *(const short8*)((const char*)lbl + sb);
      acc[ct] = __builtin_amdgcn_mfma_f32_16x16x32_bf16(ah, bh, acc[ct], 0, 0, 0);
      acc[ct] = __builtin_amdgcn_mfma_f32_16x16x32_bf16(ah, bl, acc[ct], 0, 0, 0);
      acc[ct] = __builtin_amdgcn_mfma_f32_16x16x32_bf16(al, bh, acc[ct], 0, 0, 0);
    }
  }
  // C: col = lane&15 (within tile), row = 4*(lane>>4)+j
  const int rb4 = rowbase + ((lane >> 4) << 2);
  const int cc = lane & 15;
#pragma unroll
  for (int ct = 0; ct < 4; ++ct) {  // -> p0 (bf16)
#pragma unroll
    for (int j = 0; j < 4; ++j) {
      const int r = rb4 + j;
      if (r < N_NODES) p0u[(size_t)r * HID + ct * 16 + cc] = bf16rne(acc[ct][j]);
    }
  }
#pragma unroll
  for (int ct = 4; ct < 8; ++ct) {  // -> s0b (fp32 + bias)
    const float bias = b0[(ct - 4) * 16 + cc];
#pragma unroll
    for (int j = 0; j < 4; ++j) {
      const int r = rb4 + j;
      if (r < N_NODES) s0b[(size_t)r * HID + (ct - 4) * 16 + cc] = acc[ct][j] + bias;
    }
  }
}

// ------- Layer 1 MFMA GEMM: [p1 | s1b] = h1 @ [Wneigh1 | Wself1] (+b1) ------
__global__ __launch_bounds__(256) void gemm1(
    const float* __restrict__ h1, const unsigned short* __restrict__ B1h,
    const unsigned short* __restrict__ B1l, const float* __restrict__ b1,
    unsigned short* __restrict__ p1u, float* __restrict__ s1b) {
  __shared__ unsigned short lbh[64 * 64];  // 8 KB
  __shared__ unsigned short lbl[64 * 64];  // 8 KB
  const int tid = threadIdx.x;
  {
    const uint4* gh = (const uint4*)B1h;
    const uint4* gl = (const uint4*)B1l;
    for (int i = tid; i < 512; i += 256) {
      const int o = i << 4;
      const int sw = o ^ (((o >> 7) & 7) << 4);
      *(uint4*)((char*)lbh + sw) = gh[i];
      *(uint4*)((char*)lbl + sw) = gl[i];
    }
  }
  __syncthreads();
  const int lane = tid & 63;
  const int wave = tid >> 6;
  const int rowbase = blockIdx.x * 64 + wave * 16;
  const int arow = rowbase + (lane & 15);
  const int rclamp = (arow < N_NODES) ? arow : 0;
  const int ko = (lane >> 4) << 3;

  f32x4 acc[4];
#pragma unroll
  for (int ct = 0; ct < 4; ++ct) acc[ct] = (f32x4){0.f, 0.f, 0.f, 0.f};

  for (int ks = 0; ks < 2; ++ks) {
    float av[8];
    const float* ax = h1 + (size_t)rclamp * HID + ks * 32 + ko;
    *(float4*)&av[0] = *(const float4*)ax;
    *(float4*)&av[4] = *(const float4*)(ax + 4);
    short8 ah, al;
#pragma unroll
    for (int j = 0; j < 8; ++j) {
      const unsigned short hi = bf16rne(av[j]);
      ah[j] = (short)hi;
      al[j] = (short)bf16rne(av[j] - uf(hi));
    }
    const int kb = ks * 64 + (ko << 1);
#pragma unroll
    for (int ct = 0; ct < 4; ++ct) {
      const int n = ct * 16 + (lane & 15);
      const int boff = (n << 7) + kb;
      const int sb = boff ^ (((boff >> 7) & 7) << 4);
      const short8 bh = *(const short8*)((const char*)lbh + sb);
      const short8 bl = *(const short8*)((const char*)lbl + sb);
      acc[ct] = __builtin_amdgcn_mfma_f32_16x16x32_bf16(ah, bh, acc[ct], 0, 0, 0);
      acc[ct] = __builtin_amdgcn_mfma_f32_16x16x32_bf16(ah, bl, acc[ct], 0, 0, 0);
      acc[ct] = __builtin_amdgcn_mfma_f32_16x16x32_bf16(al, bh, acc[ct], 0, 0, 0);
    }
  }
  const int rb4 = rowbase + ((lane >> 4) << 2);
  const int cc = lane & 15;
#pragma unroll
  for (int ct = 0; ct < 2; ++ct) {  // -> p1 (bf16)
#pragma unroll
    for (int j = 0; j < 4; ++j) {
      const int r = rb4 + j;
      if (r < N_NODES) p1u[(size_t)r * OUT_DIM + ct * 16 + cc] = bf16rne(acc[ct][j]);
    }
  }
#pragma unroll
  for (int ct = 2; ct < 4; ++ct) {  // -> s1b (fp32 + bias)
    const float bias = b1[(ct - 2) * 16 + cc];
#pragma unroll
    for (int j = 0; j < 4; ++j) {
      const int r = rb4 + j;
      if (r < N_NODES)
        s1b[(size_t)r * OUT_DIM + (ct - 2) * 16 + cc] = acc[ct][j] + bias;
    }
  }
}

// ------- Fused layer-0 aggregate (gather bf16) + mean + LN + ReLU -> h1 -----
__global__ __launch_bounds__(256) void aggc0(
    const int* __restrict__ sortedSrc, const int* __restrict__ off,
    const int* __restrict__ deg, const unsigned short* __restrict__ p0u,
    const float* __restrict__ s0b, const float* __restrict__ g,
    const float* __restrict__ be, float* __restrict__ h1) {
  const int lane = threadIdx.x & 63;
  const int i = blockIdx.x * 4 + (threadIdx.x >> 6);
  if (i >= N_NODES) return;
  const int st = off[i];
  const int dg = deg[i];
  float a0 = 0.f, a1 = 0.f, a2 = 0.f, a3 = 0.f;
  for (int base = 0; base < dg; base += 64) {
    const int cnt = min(64, dg - base);
    const int idx = (lane < cnt) ? sortedSrc[st + base + lane] : 0;
    int j = 0;
    for (; j + 3 < cnt; j += 4) {
      const int s0 = __shfl(idx, j);
      const int s1 = __shfl(idx, j + 1);
      const int s2 = __shfl(idx, j + 2);
      const int s3 = __shfl(idx, j + 3);
      a0 += uf(p0u[(size_t)s0 * HID + lane]);
      a1 += uf(p0u[(size_t)s1 * HID + lane]);
      a2 += uf(p0u[(size_t)s2 * HID + lane]);
      a3 += uf(p0u[(size_t)s3 * HID + lane]);
    }
    for (; j < cnt; ++j) a0 += uf(p0u[(size_t)__shfl(idx, j) * HID + lane]);
  }
  const float acc = (a0 + a1) + (a2 + a3);
  const float inv = 1.0f / fmaxf((float)dg, 1.0f);
  const float z = s0b[(size_t)i * HID + lane] + acc * inv;
  float m = z;
#pragma unroll
  for (int mk = 1; mk < 64; mk <<= 1) m += __shfl_xor(m, mk);
  m *= (1.0f / 64.0f);
  const float dz = z - m;
  float v = dz * dz;
#pragma unroll
  for (int mk = 1; mk < 64; mk <<= 1) v += __shfl_xor(v, mk);
  v *= (1.0f / 64.0f);
  const float zn = dz * rsqrtf(v + LN_EPS) * g[lane] + be[lane];
  h1[(size_t)i * HID + lane] = fmaxf(zn, 0.0f);
}

// ------- Fused layer-1 aggregate (gather bf16) + mean + LN + ReLU -> out ----
__global__ __launch_bounds__(256) void aggc1(
    const int* __restrict__ sortedSrc, const int* __restrict__ off,
    const int* __restrict__ deg, const unsigned short* __restrict__ p1u,
    const float* __restrict__ s1b, const float* __restrict__ g,
    const float* __restrict__ be, float* __restrict__ out) {
  const int lane = threadIdx.x & 63;
  const int half = lane >> 5;
  const int f = lane & 31;
  const int i = blockIdx.x * 4 + (threadIdx.x >> 6);
  if (i >= N_NODES) return;
  const int st = off[i];
  const int dg = deg[i];
  float a0 = 0.f, a1 = 0.f, a2 = 0.f, a3 = 0.f;
  for (int base = 0; base < dg; base += 64) {
    const int cnt = min(64, dg - base);
    const int idx = (lane < cnt) ? sortedSrc[st + base + lane] : 0;
    for (int j = 0; j < cnt; j += 8) {
      const int j0 = j + half, j1 = j + 2 + half, j2 = j + 4 + half,
                j3 = j + 6 + half;
      const int s0 = __shfl(idx, j0 & 63);
      const int s1 = __shfl(idx, j1 & 63);
      const int s2 = __shfl(idx, j2 & 63);
      const int s3 = __shfl(idx, j3 & 63);
      if (j0 < cnt) a0 += uf(p1u[(size_t)s0 * OUT_DIM + f]);
      if (j1 < cnt) a1 += uf(p1u[(size_t)s1 * OUT_DIM + f]);
      if (j2 < cnt) a2 += uf(p1u[(size_t)s2 * OUT_DIM + f]);
      if (j3 < cnt) a3 += uf(p1u[(size_t)s3 * OUT_DIM + f]);
    }
  }
  float acc = (a0 + a1) + (a2 + a3);
  acc += __shfl_xor(acc, 32);
  const float inv = 1.0f / fmaxf((float)dg, 1.0f);
  const float z = s1b[(size_t)i * OUT_DIM + f] + acc * inv;
  float m = z;
#pragma unroll
  for (int mk = 1; mk < 32; mk <<= 1) m += __shfl_xor(m, mk);
  m *= (1.0f / 32.0f);
  const float dz = z - m;
  float v = dz * dz;
#pragma unroll
  for (int mk = 1; mk < 32; mk <<= 1) v += __shfl_xor(v, mk);
  v *= (1.0f / 32.0f);
  float zn = dz * rsqrtf(v + LN_EPS) * g[f] + be[f];
  if (half == 0) out[(size_t)i * OUT_DIM + f] = fmaxf(zn, 0.0f);
}

extern "C" void kernel_launch(void* const* d_in, const int* in_sizes, int n_in,
                              void* d_out, int out_size, void* d_ws, size_t ws_size,
                              hipStream_t stream) {
  const float* x       = (const float*)d_in[0];
  const int*   edges   = (const int*)d_in[1];
  const float* Wself0  = (const float*)d_in[2];
  const float* Wneigh0 = (const float*)d_in[3];
  const float* b0      = (const float*)d_in[4];
  const float* g0      = (const float*)d_in[5];
  const float* be0     = (const float*)d_in[6];
  const float* Wself1  = (const float*)d_in[7];
  const float* Wneigh1 = (const float*)d_in[8];
  const float* b1      = (const float*)d_in[9];
  const float* g1      = (const float*)d_in[10];
  const float* be1     = (const float*)d_in[11];

  int* flag      = (int*)d_ws;
  int* sortedSrc = flag + 64;
  int* pos       = sortedSrc + N_EDGES;
  int* off       = pos + N_EDGES;
  int* deg       = off + N_NODES;
  int* bsum      = deg + N_NODES;
  int* boff      = bsum + 128;
  unsigned short* B0h = (unsigned short*)(boff + 128);  // 16384
  unsigned short* B0l = B0h + 128 * 128;
  unsigned short* B1h = B0l + 128 * 128;                // 4096
  unsigned short* B1l = B1h + 64 * 64;
  unsigned short* p0u = B1l + 64 * 64;                  // N*64 bf16
  float* s0b = (float*)(p0u + (size_t)N_NODES * HID);   // N*64 f32
  float* h1  = s0b + (size_t)N_NODES * HID;             // N*64 f32
  unsigned short* p1u = p0u;                            // overlay (p0 dead)
  float* s1b = s0b;                                     // overlay (s0b dead)

  hipMemsetAsync(deg, 0, N_NODES * sizeof(int), stream);

  detect_edges<<<1, 256, 0, stream>>>(edges, flag);
  convW<<<80, 256, 0, stream>>>(Wneigh0, Wself0, Wneigh1, Wself1,
                                B0h, B0l, B1h, B1l);
  hist<<<1024, 256, 0, stream>>>(edges, flag, deg, pos);
  scanA<<<N_SCAN_BLOCKS, 256, 0, stream>>>(deg, off, bsum);
  scanB<<<1, 64, 0, stream>>>(bsum, boff);
  scanC<<<(N_NODES + 255) / 256, 256, 0, stream>>>(off, boff);
  fill<<<1024, 256, 0, stream>>>(edges, flag, off, pos, sortedSrc);

  gemm0<<<(N_NODES + 63) / 64, 256, 0, stream>>>(x, B0h, B0l, b0, p0u, s0b);
  aggc0<<<(N_NODES + 3) / 4, 256, 0, stream>>>(sortedSrc, off, deg, p0u, s0b,
                                               g0, be0, h1);
  gemm1<<<(N_NODES + 63) / 64, 256, 0, stream>>>(h1, B1h, B1l, b1, p1u, s1b);
  aggc1<<<(N_NODES + 3) / 4, 256, 0, stream>>>(sortedSrc, off, deg, p1u, s1b,
                                               g1, be1, (float*)d_out);
}

// Round 6
// 253.051 us; speedup vs baseline: 2.9134x; 1.1249x over previous
//
#include <hip/hip_runtime.h>
#include <hip/hip_bf16.h>

#define N_NODES 100000
#define N_EDGES 1600000
#define IN_DIM 128
#define HID 64
#define OUT_DIM 32
#define LN_EPS 1e-5f
#define SCAN_CHUNK 1024
#define N_SCAN_BLOCKS ((N_NODES + SCAN_CHUNK - 1) / SCAN_CHUNK)  // 98

typedef __attribute__((ext_vector_type(8))) short short8;
typedef __attribute__((ext_vector_type(4))) float f32x4;

__device__ __forceinline__ float uf(unsigned short u) {
  return __uint_as_float(((unsigned int)u) << 16);
}
__device__ __forceinline__ float uflo(unsigned int u) {  // low bf16 of word
  return __uint_as_float(u << 16);
}
__device__ __forceinline__ float ufhi(unsigned int u) {  // high bf16 of word
  return __uint_as_float(u & 0xffff0000u);
}
__device__ __forceinline__ unsigned short bf16rne(float f) {
  unsigned int u = __float_as_uint(f);
  unsigned int r = u + 0x7fffu + ((u >> 16) & 1u);
  return (unsigned short)(r >> 16);
}

// ---------- Edge dtype detect: int64 (high words all 0) vs int32 ------------
__global__ void detect_edges(const int* __restrict__ w, int* __restrict__ flag) {
  __shared__ int any;
  if (threadIdx.x == 0) any = 0;
  __syncthreads();
  if (w[2 * threadIdx.x + 1] != 0) any = 1;  // benign race, all write 1
  __syncthreads();
  if (threadIdx.x == 0) flag[0] = any ? 0 : 1;  // 1 => int64 layout
}

// ---------- Weight split: B0 [128n][128k] hi/lo, B1 [64n][64k] hi/lo --------
__global__ __launch_bounds__(256) void convW(
    const float* __restrict__ Wn0, const float* __restrict__ Ws0,
    const float* __restrict__ Wn1, const float* __restrict__ Ws1,
    unsigned short* __restrict__ B0h, unsigned short* __restrict__ B0l,
    unsigned short* __restrict__ B1h, unsigned short* __restrict__ B1l) {
  const int i = blockIdx.x * 256 + threadIdx.x;
  if (i < 128 * 128) {
    const int n = i >> 7, k = i & 127;
    const float w = (n < 64) ? Wn0[k * 64 + n] : Ws0[k * 64 + (n - 64)];
    const unsigned short hi = bf16rne(w);
    B0h[i] = hi;
    B0l[i] = bf16rne(w - uf(hi));
  } else if (i < 128 * 128 + 64 * 64) {
    const int j = i - 128 * 128;
    const int n = j >> 6, k = j & 63;
    const float w = (n < 32) ? Wn1[k * 32 + n] : Ws1[k * 32 + (n - 32)];
    const unsigned short hi = bf16rne(w);
    B1h[j] = hi;
    B1l[j] = bf16rne(w - uf(hi));
  }
}

// ---------------- Histogram over dst + per-edge position --------------------
__global__ __launch_bounds__(256) void hist(
    const int* __restrict__ w, const int* __restrict__ flag,
    int* __restrict__ deg, int* __restrict__ pos) {
  const int i64 = flag[0];
  const int npairs = N_EDGES / 2;
  for (int p = blockIdx.x * 256 + threadIdx.x; p < npairs;
       p += gridDim.x * 256) {
    int d0, d1;
    if (i64) {
      const int4 v = *(const int4*)(w + 2 * (size_t)N_EDGES + 4 * (size_t)p);
      d0 = v.x;
      d1 = v.z;
    } else {
      const int2 v = *(const int2*)(w + (size_t)N_EDGES + 2 * (size_t)p);
      d0 = v.x;
      d1 = v.y;
    }
    const int p0 = atomicAdd(&deg[d0], 1);
    const int p1 = atomicAdd(&deg[d1], 1);
    pos[2 * p] = p0;
    pos[2 * p + 1] = p1;
  }
}

// ---------------- Scan stage A: per-block (1024 elems) local ex-scan --------
__global__ __launch_bounds__(256) void scanA(
    const int* __restrict__ deg, int* __restrict__ off,
    int* __restrict__ bsum) {
  __shared__ int lds[256];
  const int t = threadIdx.x;
  const int base = blockIdx.x * SCAN_CHUNK;
  int v[4];
  int s = 0;
#pragma unroll
  for (int j = 0; j < 4; ++j) {
    const int idx = base + t * 4 + j;
    v[j] = (idx < N_NODES) ? deg[idx] : 0;
    s += v[j];
  }
  lds[t] = s;
  __syncthreads();
  for (int o = 1; o < 256; o <<= 1) {
    const int val = (t >= o) ? lds[t - o] : 0;
    __syncthreads();
    lds[t] += val;
    __syncthreads();
  }
  int run = lds[t] - s;
  if (t == 255) bsum[blockIdx.x] = lds[255];
#pragma unroll
  for (int j = 0; j < 4; ++j) {
    const int idx = base + t * 4 + j;
    if (idx < N_NODES) off[idx] = run;
    run += v[j];
  }
}

// ---------------- Scan stage B: 1-wave shuffle scan of 98 block sums --------
__global__ void scanB(const int* __restrict__ bsum, int* __restrict__ boff) {
  const int l = threadIdx.x;
  const int i0 = 2 * l, i1 = 2 * l + 1;
  const int v0 = (i0 < N_SCAN_BLOCKS) ? bsum[i0] : 0;
  const int v1 = (i1 < N_SCAN_BLOCKS) ? bsum[i1] : 0;
  int s = v0 + v1;
#pragma unroll
  for (int o = 1; o < 64; o <<= 1) {
    const int t = __shfl_up(s, o);
    if (l >= o) s += t;
  }
  const int excl = s - (v0 + v1);
  if (i0 < N_SCAN_BLOCKS) boff[i0] = excl;
  if (i1 < N_SCAN_BLOCKS) boff[i1] = excl + v0;
}

// ---------------- Scan stage C: add block offsets ---------------------------
__global__ __launch_bounds__(256) void scanC(int* __restrict__ off,
                                             const int* __restrict__ boff) {
  const int idx = blockIdx.x * 256 + threadIdx.x;
  if (idx < N_NODES) off[idx] += boff[idx / SCAN_CHUNK];
}

// ---------------- Fill: sortedSrc[off[d]+pos[e]] = src[e] (no atomics) ------
__global__ __launch_bounds__(256) void fill(
    const int* __restrict__ w, const int* __restrict__ flag,
    const int* __restrict__ off, const int* __restrict__ pos,
    int* __restrict__ sortedSrc) {
  const int i64 = flag[0];
  const int npairs = N_EDGES / 2;
  for (int p = blockIdx.x * 256 + threadIdx.x; p < npairs;
       p += gridDim.x * 256) {
    int s0, s1, d0, d1;
    if (i64) {
      const int4 vs = *(const int4*)(w + 4 * (size_t)p);
      const int4 vd = *(const int4*)(w + 2 * (size_t)N_EDGES + 4 * (size_t)p);
      s0 = vs.x; s1 = vs.z;
      d0 = vd.x; d1 = vd.z;
    } else {
      const int2 vs = *(const int2*)(w + 2 * (size_t)p);
      const int2 vd = *(const int2*)(w + (size_t)N_EDGES + 2 * (size_t)p);
      s0 = vs.x; s1 = vs.y;
      d0 = vd.x; d1 = vd.y;
    }
    const int2 pp = *(const int2*)(pos + 2 * (size_t)p);
    sortedSrc[off[d0] + pp.x] = s0;
    sortedSrc[off[d1] + pp.y] = s1;
  }
}

// ------- Layer 0 MFMA GEMM: [p0 | s0b] = x @ [Wneigh0 | Wself0] (+b0) -------
__global__ __launch_bounds__(256) void gemm0(
    const float* __restrict__ x, const unsigned short* __restrict__ B0h,
    const unsigned short* __restrict__ B0l, const float* __restrict__ b0,
    unsigned short* __restrict__ p0u, float* __restrict__ s0b) {
  __shared__ unsigned short lbh[128 * 128];  // 32 KB
  __shared__ unsigned short lbl[128 * 128];  // 32 KB
  const int tid = threadIdx.x;
  {
    const uint4* gh = (const uint4*)B0h;
    const uint4* gl = (const uint4*)B0l;
    for (int i = tid; i < 2048; i += 256) {
      const int o = i << 4;
      const int sw = o ^ (((o >> 8) & 7) << 4);
      *(uint4*)((char*)lbh + sw) = gh[i];
      *(uint4*)((char*)lbl + sw) = gl[i];
    }
  }
  __syncthreads();
  const int lane = tid & 63;
  const int wave = tid >> 6;
  const int rowbase = blockIdx.x * 64 + wave * 16;
  const int arow = rowbase + (lane & 15);
  const int rclamp = (arow < N_NODES) ? arow : 0;
  const int ko = (lane >> 4) << 3;  // 0,8,16,24

  f32x4 acc[8];
#pragma unroll
  for (int ct = 0; ct < 8; ++ct) acc[ct] = (f32x4){0.f, 0.f, 0.f, 0.f};

  for (int ks = 0; ks < 4; ++ks) {
    float av[8];
    const float* ax = x + (size_t)rclamp * IN_DIM + ks * 32 + ko;
    *(float4*)&av[0] = *(const float4*)ax;
    *(float4*)&av[4] = *(const float4*)(ax + 4);
    short8 ah, al;
#pragma unroll
    for (int j = 0; j < 8; ++j) {
      const unsigned short hi = bf16rne(av[j]);
      ah[j] = (short)hi;
      al[j] = (short)bf16rne(av[j] - uf(hi));
    }
    const int kb = ks * 64 + (ko << 1);
#pragma unroll
    for (int ct = 0; ct < 8; ++ct) {
      const int n = ct * 16 + (lane & 15);
      const int boff = (n << 8) + kb;
      const int sb = boff ^ (((boff >> 8) & 7) << 4);
      const short8 bh = *(const short8*)((const char*)lbh + sb);
      const short8 bl = *(const short8*)((const char*)lbl + sb);
      acc[ct] = __builtin_amdgcn_mfma_f32_16x16x32_bf16(ah, bh, acc[ct], 0, 0, 0);
      acc[ct] = __builtin_amdgcn_mfma_f32_16x16x32_bf16(ah, bl, acc[ct], 0, 0, 0);
      acc[ct] = __builtin_amdgcn_mfma_f32_16x16x32_bf16(al, bh, acc[ct], 0, 0, 0);
    }
  }
  const int rb4 = rowbase + ((lane >> 4) << 2);
  const int cc = lane & 15;
#pragma unroll
  for (int ct = 0; ct < 4; ++ct) {  // -> p0 (bf16)
#pragma unroll
    for (int j = 0; j < 4; ++j) {
      const int r = rb4 + j;
      if (r < N_NODES) p0u[(size_t)r * HID + ct * 16 + cc] = bf16rne(acc[ct][j]);
    }
  }
#pragma unroll
  for (int ct = 4; ct < 8; ++ct) {  // -> s0b (fp32 + bias)
    const float bias = b0[(ct - 4) * 16 + cc];
#pragma unroll
    for (int j = 0; j < 4; ++j) {
      const int r = rb4 + j;
      if (r < N_NODES) s0b[(size_t)r * HID + (ct - 4) * 16 + cc] = acc[ct][j] + bias;
    }
  }
}

// ------- Layer 1 MFMA GEMM: [p1 | s1b] = h1 @ [Wneigh1 | Wself1] (+b1) ------
__global__ __launch_bounds__(256) void gemm1(
    const float* __restrict__ h1, const unsigned short* __restrict__ B1h,
    const unsigned short* __restrict__ B1l, const float* __restrict__ b1,
    unsigned short* __restrict__ p1u, float* __restrict__ s1b) {
  __shared__ unsigned short lbh[64 * 64];  // 8 KB
  __shared__ unsigned short lbl[64 * 64];  // 8 KB
  const int tid = threadIdx.x;
  {
    const uint4* gh = (const uint4*)B1h;
    const uint4* gl = (const uint4*)B1l;
    for (int i = tid; i < 512; i += 256) {
      const int o = i << 4;
      const int sw = o ^ (((o >> 7) & 7) << 4);
      *(uint4*)((char*)lbh + sw) = gh[i];
      *(uint4*)((char*)lbl + sw) = gl[i];
    }
  }
  __syncthreads();
  const int lane = tid & 63;
  const int wave = tid >> 6;
  const int rowbase = blockIdx.x * 64 + wave * 16;
  const int arow = rowbase + (lane & 15);
  const int rclamp = (arow < N_NODES) ? arow : 0;
  const int ko = (lane >> 4) << 3;

  f32x4 acc[4];
#pragma unroll
  for (int ct = 0; ct < 4; ++ct) acc[ct] = (f32x4){0.f, 0.f, 0.f, 0.f};

  for (int ks = 0; ks < 2; ++ks) {
    float av[8];
    const float* ax = h1 + (size_t)rclamp * HID + ks * 32 + ko;
    *(float4*)&av[0] = *(const float4*)ax;
    *(float4*)&av[4] = *(const float4*)(ax + 4);
    short8 ah, al;
#pragma unroll
    for (int j = 0; j < 8; ++j) {
      const unsigned short hi = bf16rne(av[j]);
      ah[j] = (short)hi;
      al[j] = (short)bf16rne(av[j] - uf(hi));
    }
    const int kb = ks * 64 + (ko << 1);
#pragma unroll
    for (int ct = 0; ct < 4; ++ct) {
      const int n = ct * 16 + (lane & 15);
      const int boff = (n << 7) + kb;
      const int sb = boff ^ (((boff >> 7) & 7) << 4);
      const short8 bh = *(const short8*)((const char*)lbh + sb);
      const short8 bl = *(const short8*)((const char*)lbl + sb);
      acc[ct] = __builtin_amdgcn_mfma_f32_16x16x32_bf16(ah, bh, acc[ct], 0, 0, 0);
      acc[ct] = __builtin_amdgcn_mfma_f32_16x16x32_bf16(ah, bl, acc[ct], 0, 0, 0);
      acc[ct] = __builtin_amdgcn_mfma_f32_16x16x32_bf16(al, bh, acc[ct], 0, 0, 0);
    }
  }
  const int rb4 = rowbase + ((lane >> 4) << 2);
  const int cc = lane & 15;
#pragma unroll
  for (int ct = 0; ct < 2; ++ct) {  // -> p1 (bf16)
#pragma unroll
    for (int j = 0; j < 4; ++j) {
      const int r = rb4 + j;
      if (r < N_NODES) p1u[(size_t)r * OUT_DIM + ct * 16 + cc] = bf16rne(acc[ct][j]);
    }
  }
#pragma unroll
  for (int ct = 2; ct < 4; ++ct) {  // -> s1b (fp32 + bias)
    const float bias = b1[(ct - 2) * 16 + cc];
#pragma unroll
    for (int j = 0; j < 4; ++j) {
      const int r = rb4 + j;
      if (r < N_NODES)
        s1b[(size_t)r * OUT_DIM + (ct - 2) * 16 + cc] = acc[ct][j] + bias;
    }
  }
}

// ------- Fused layer-0 aggregate + mean + LN + ReLU -> h1 -------------------
// One node per wave. Lane l = (edge-group g = l>>3, slice s = l&7).
// One uint4 load gathers 8 edges (8 lines) simultaneously; mask-FMA remainder.
__global__ __launch_bounds__(256) void aggc0(
    const int* __restrict__ sortedSrc, const int* __restrict__ off,
    const int* __restrict__ deg, const unsigned short* __restrict__ p0u,
    const float* __restrict__ s0b, const float* __restrict__ g,
    const float* __restrict__ be, float* __restrict__ h1) {
  const int lane = threadIdx.x & 63;
  const int grp = lane >> 3;   // 0..7  edge group
  const int sl = lane & 7;     // 0..7  feature slice (8 feats)
  const int i = blockIdx.x * 4 + (threadIdx.x >> 6);
  if (i >= N_NODES) return;
  const int st = off[i];
  const int dg = deg[i];
  float acc[8];
#pragma unroll
  for (int f = 0; f < 8; ++f) acc[f] = 0.f;

  for (int base = 0; base < dg; base += 64) {
    const int cnt = min(64, dg - base);
    const int idx = (lane < cnt) ? sortedSrc[st + base + lane] : 0;
    for (int j = 0; j * 8 < cnt; ++j) {
      const int e = j * 8 + grp;
      const float msk = (e < cnt) ? 1.f : 0.f;
      const int srcn = __shfl(idx, min(e, cnt - 1));
      const uint4 q = *(const uint4*)(p0u + (size_t)srcn * HID + sl * 8);
      acc[0] = fmaf(msk, uflo(q.x), acc[0]);
      acc[1] = fmaf(msk, ufhi(q.x), acc[1]);
      acc[2] = fmaf(msk, uflo(q.y), acc[2]);
      acc[3] = fmaf(msk, ufhi(q.y), acc[3]);
      acc[4] = fmaf(msk, uflo(q.z), acc[4]);
      acc[5] = fmaf(msk, ufhi(q.z), acc[5]);
      acc[6] = fmaf(msk, uflo(q.w), acc[6]);
      acc[7] = fmaf(msk, ufhi(q.w), acc[7]);
    }
  }
  // fold edge groups (xor over lane bits 3,4,5)
#pragma unroll
  for (int mk = 8; mk < 64; mk <<= 1) {
#pragma unroll
    for (int f = 0; f < 8; ++f) acc[f] += __shfl_xor(acc[f], mk);
  }
  // z = s0b + mean
  const float inv = 1.0f / fmaxf((float)dg, 1.0f);
  float z[8];
  const float4 sb0 = *(const float4*)(s0b + (size_t)i * HID + sl * 8);
  const float4 sb1 = *(const float4*)(s0b + (size_t)i * HID + sl * 8 + 4);
  z[0] = sb0.x + acc[0] * inv; z[1] = sb0.y + acc[1] * inv;
  z[2] = sb0.z + acc[2] * inv; z[3] = sb0.w + acc[3] * inv;
  z[4] = sb1.x + acc[4] * inv; z[5] = sb1.y + acc[5] * inv;
  z[6] = sb1.z + acc[6] * inv; z[7] = sb1.w + acc[7] * inv;
  // LN over 64 feats: local partial + xor over slice bits 0,1,2
  float pm = 0.f;
#pragma unroll
  for (int f = 0; f < 8; ++f) pm += z[f];
#pragma unroll
  for (int mk = 1; mk < 8; mk <<= 1) pm += __shfl_xor(pm, mk);
  const float mean = pm * (1.0f / 64.0f);
  float pv = 0.f;
#pragma unroll
  for (int f = 0; f < 8; ++f) {
    z[f] -= mean;
    pv += z[f] * z[f];
  }
#pragma unroll
  for (int mk = 1; mk < 8; mk <<= 1) pv += __shfl_xor(pv, mk);
  const float rstd = rsqrtf(pv * (1.0f / 64.0f) + LN_EPS);
  if (grp == 0) {
    const float4 gv0 = *(const float4*)(g + sl * 8);
    const float4 gv1 = *(const float4*)(g + sl * 8 + 4);
    const float4 bv0 = *(const float4*)(be + sl * 8);
    const float4 bv1 = *(const float4*)(be + sl * 8 + 4);
    float4 o0, o1;
    o0.x = fmaxf(z[0] * rstd * gv0.x + bv0.x, 0.f);
    o0.y = fmaxf(z[1] * rstd * gv0.y + bv0.y, 0.f);
    o0.z = fmaxf(z[2] * rstd * gv0.z + bv0.z, 0.f);
    o0.w = fmaxf(z[3] * rstd * gv0.w + bv0.w, 0.f);
    o1.x = fmaxf(z[4] * rstd * gv1.x + bv1.x, 0.f);
    o1.y = fmaxf(z[5] * rstd * gv1.y + bv1.y, 0.f);
    o1.z = fmaxf(z[6] * rstd * gv1.z + bv1.z, 0.f);
    o1.w = fmaxf(z[7] * rstd * gv1.w + bv1.w, 0.f);
    *(float4*)(h1 + (size_t)i * HID + sl * 8) = o0;
    *(float4*)(h1 + (size_t)i * HID + sl * 8 + 4) = o1;
  }
}

// ------- Fused layer-1 aggregate + mean + LN + ReLU -> out ------------------
// One node per wave. Lane l = (edge-group g = l>>2, slice s = l&3).
// One uint4 load gathers 16 edges (16 lines) simultaneously.
__global__ __launch_bounds__(256) void aggc1(
    const int* __restrict__ sortedSrc, const int* __restrict__ off,
    const int* __restrict__ deg, const unsigned short* __restrict__ p1u,
    const float* __restrict__ s1b, const float* __restrict__ g,
    const float* __restrict__ be, float* __restrict__ out) {
  const int lane = threadIdx.x & 63;
  const int grp = lane >> 2;   // 0..15 edge group
  const int sl = lane & 3;     // 0..3  feature slice (8 feats)
  const int i = blockIdx.x * 4 + (threadIdx.x >> 6);
  if (i >= N_NODES) return;
  const int st = off[i];
  const int dg = deg[i];
  float acc[8];
#pragma unroll
  for (int f = 0; f < 8; ++f) acc[f] = 0.f;

  for (int base = 0; base < dg; base += 64) {
    const int cnt = min(64, dg - base);
    const int idx = (lane < cnt) ? sortedSrc[st + base + lane] : 0;
    for (int j = 0; j * 16 < cnt; ++j) {
      const int e = j * 16 + grp;
      const float msk = (e < cnt) ? 1.f : 0.f;
      const int srcn = __shfl(idx, min(e, cnt - 1));
      const uint4 q = *(const uint4*)(p1u + (size_t)srcn * OUT_DIM + sl * 8);
      acc[0] = fmaf(msk, uflo(q.x), acc[0]);
      acc[1] = fmaf(msk, ufhi(q.x), acc[1]);
      acc[2] = fmaf(msk, uflo(q.y), acc[2]);
      acc[3] = fmaf(msk, ufhi(q.y), acc[3]);
      acc[4] = fmaf(msk, uflo(q.z), acc[4]);
      acc[5] = fmaf(msk, ufhi(q.z), acc[5]);
      acc[6] = fmaf(msk, uflo(q.w), acc[6]);
      acc[7] = fmaf(msk, ufhi(q.w), acc[7]);
    }
  }
  // fold edge groups (xor over lane bits 2..5)
#pragma unroll
  for (int mk = 4; mk < 64; mk <<= 1) {
#pragma unroll
    for (int f = 0; f < 8; ++f) acc[f] += __shfl_xor(acc[f], mk);
  }
  const float inv = 1.0f / fmaxf((float)dg, 1.0f);
  float z[8];
  const float4 sb0 = *(const float4*)(s1b + (size_t)i * OUT_DIM + sl * 8);
  const float4 sb1 = *(const float4*)(s1b + (size_t)i * OUT_DIM + sl * 8 + 4);
  z[0] = sb0.x + acc[0] * inv; z[1] = sb0.y + acc[1] * inv;
  z[2] = sb0.z + acc[2] * inv; z[3] = sb0.w + acc[3] * inv;
  z[4] = sb1.x + acc[4] * inv; z[5] = sb1.y + acc[5] * inv;
  z[6] = sb1.z + acc[6] * inv; z[7] = sb1.w + acc[7] * inv;
  // LN over 32 feats: local partial + xor over slice bits 0,1
  float pm = 0.f;
#pragma unroll
  for (int f = 0; f < 8; ++f) pm += z[f];
#pragma unroll
  for (int mk = 1; mk < 4; mk <<= 1) pm += __shfl_xor(pm, mk);
  const float mean = pm * (1.0f / 32.0f);
  float pv = 0.f;
#pragma unroll
  for (int f = 0; f < 8; ++f) {
    z[f] -= mean;
    pv += z[f] * z[f];
  }
#pragma unroll
  for (int mk = 1; mk < 4; mk <<= 1) pv += __shfl_xor(pv, mk);
  const float rstd = rsqrtf(pv * (1.0f / 32.0f) + LN_EPS);
  if (grp == 0) {
    const float4 gv0 = *(const float4*)(g + sl * 8);
    const float4 gv1 = *(const float4*)(g + sl * 8 + 4);
    const float4 bv0 = *(const float4*)(be + sl * 8);
    const float4 bv1 = *(const float4*)(be + sl * 8 + 4);
    float4 o0, o1;
    o0.x = fmaxf(z[0] * rstd * gv0.x + bv0.x, 0.f);
    o0.y = fmaxf(z[1] * rstd * gv0.y + bv0.y, 0.f);
    o0.z = fmaxf(z[2] * rstd * gv0.z + bv0.z, 0.f);
    o0.w = fmaxf(z[3] * rstd * gv0.w + bv0.w, 0.f);
    o1.x = fmaxf(z[4] * rstd * gv1.x + bv1.x, 0.f);
    o1.y = fmaxf(z[5] * rstd * gv1.y + bv1.y, 0.f);
    o1.z = fmaxf(z[6] * rstd * gv1.z + bv1.z, 0.f);
    o1.w = fmaxf(z[7] * rstd * gv1.w + bv1.w, 0.f);
    *(float4*)(out + (size_t)i * OUT_DIM + sl * 8) = o0;
    *(float4*)(out + (size_t)i * OUT_DIM + sl * 8 + 4) = o1;
  }
}

extern "C" void kernel_launch(void* const* d_in, const int* in_sizes, int n_in,
                              void* d_out, int out_size, void* d_ws, size_t ws_size,
                              hipStream_t stream) {
  const float* x       = (const float*)d_in[0];
  const int*   edges   = (const int*)d_in[1];
  const float* Wself0  = (const float*)d_in[2];
  const float* Wneigh0 = (const float*)d_in[3];
  const float* b0      = (const float*)d_in[4];
  const float* g0      = (const float*)d_in[5];
  const float* be0     = (const float*)d_in[6];
  const float* Wself1  = (const float*)d_in[7];
  const float* Wneigh1 = (const float*)d_in[8];
  const float* b1      = (const float*)d_in[9];
  const float* g1      = (const float*)d_in[10];
  const float* be1     = (const float*)d_in[11];

  int* flag      = (int*)d_ws;
  int* sortedSrc = flag + 64;
  int* pos       = sortedSrc + N_EDGES;
  int* off       = pos + N_EDGES;
  int* deg       = off + N_NODES;
  int* bsum      = deg + N_NODES;
  int* boff      = bsum + 128;
  unsigned short* B0h = (unsigned short*)(boff + 128);  // 16384
  unsigned short* B0l = B0h + 128 * 128;
  unsigned short* B1h = B0l + 128 * 128;                // 4096
  unsigned short* B1l = B1h + 64 * 64;
  unsigned short* p0u = B1l + 64 * 64;                  // N*64 bf16
  float* s0b = (float*)(p0u + (size_t)N_NODES * HID);   // N*64 f32
  float* h1  = s0b + (size_t)N_NODES * HID;             // N*64 f32
  unsigned short* p1u = p0u;                            // overlay (p0 dead)
  float* s1b = s0b;                                     // overlay (s0b dead)

  hipMemsetAsync(deg, 0, N_NODES * sizeof(int), stream);

  detect_edges<<<1, 256, 0, stream>>>(edges, flag);
  convW<<<80, 256, 0, stream>>>(Wneigh0, Wself0, Wneigh1, Wself1,
                                B0h, B0l, B1h, B1l);
  hist<<<1024, 256, 0, stream>>>(edges, flag, deg, pos);
  scanA<<<N_SCAN_BLOCKS, 256, 0, stream>>>(deg, off, bsum);
  scanB<<<1, 64, 0, stream>>>(bsum, boff);
  scanC<<<(N_NODES + 255) / 256, 256, 0, stream>>>(off, boff);
  fill<<<1024, 256, 0, stream>>>(edges, flag, off, pos, sortedSrc);

  gemm0<<<(N_NODES + 63) / 64, 256, 0, stream>>>(x, B0h, B0l, b0, p0u, s0b);
  aggc0<<<(N_NODES + 3) / 4, 256, 0, stream>>>(sortedSrc, off, deg, p0u, s0b,
                                               g0, be0, h1);
  gemm1<<<(N_NODES + 63) / 64, 256, 0, stream>>>(h1, B1h, B1l, b1, p1u, s1b);
  aggc1<<<(N_NODES + 3) / 4, 256, 0, stream>>>(sortedSrc, off, deg, p1u, s1b,
                                               g1, be1, (float*)d_out);
}

// Round 7
// 207.447 us; speedup vs baseline: 3.5538x; 1.2198x over previous
//
#include <hip/hip_runtime.h>
#include <hip/hip_bf16.h>

#define N_NODES 100000
#define N_EDGES 1600000
#define IN_DIM 128
#define HID 64
#define OUT_DIM 32
#define LN_EPS 1e-5f
#define NBKT 782            // ceil(100000/128) coarse buckets (128 nodes each)
#define NPBLK 500           // partition blocks
#define PAIRS_PER_BLK 1600  // 500*1600*2 = 1.6M edges

typedef __attribute__((ext_vector_type(8))) short short8;
typedef __attribute__((ext_vector_type(4))) float f32x4;

__device__ __forceinline__ float uf(unsigned short u) {
  return __uint_as_float(((unsigned int)u) << 16);
}
__device__ __forceinline__ float uflo(unsigned int u) {
  return __uint_as_float(u << 16);
}
__device__ __forceinline__ float ufhi(unsigned int u) {
  return __uint_as_float(u & 0xffff0000u);
}
__device__ __forceinline__ unsigned short bf16rne(float f) {
  unsigned int u = __float_as_uint(f);
  unsigned int r = u + 0x7fffu + ((u >> 16) & 1u);
  return (unsigned short)(r >> 16);
}

// ---------- Edge dtype detect: int64 (high words all 0) vs int32 ------------
__global__ void detect_edges(const int* __restrict__ w, int* __restrict__ flag) {
  __shared__ int any;
  if (threadIdx.x == 0) any = 0;
  __syncthreads();
  if (w[2 * threadIdx.x + 1] != 0) any = 1;
  __syncthreads();
  if (threadIdx.x == 0) flag[0] = any ? 0 : 1;  // 1 => int64 layout
}

// ---------- Weight split: B0 [128n][128k] hi/lo, B1 [64n][64k] hi/lo --------
__global__ __launch_bounds__(256) void convW(
    const float* __restrict__ Wn0, const float* __restrict__ Ws0,
    const float* __restrict__ Wn1, const float* __restrict__ Ws1,
    unsigned short* __restrict__ B0h, unsigned short* __restrict__ B0l,
    unsigned short* __restrict__ B1h, unsigned short* __restrict__ B1l) {
  const int i = blockIdx.x * 256 + threadIdx.x;
  if (i < 128 * 128) {
    const int n = i >> 7, k = i & 127;
    const float w = (n < 64) ? Wn0[k * 64 + n] : Ws0[k * 64 + (n - 64)];
    const unsigned short hi = bf16rne(w);
    B0h[i] = hi;
    B0l[i] = bf16rne(w - uf(hi));
  } else if (i < 128 * 128 + 64 * 64) {
    const int j = i - 128 * 128;
    const int n = j >> 6, k = j & 63;
    const float w = (n < 32) ? Wn1[k * 32 + n] : Ws1[k * 32 + (n - 32)];
    const unsigned short hi = bf16rne(w);
    B1h[j] = hi;
    B1l[j] = bf16rne(w - uf(hi));
  }
}

// ---------- Phase A: per-block coarse histogram + coalesced reservation -----
__global__ __launch_bounds__(256) void part_count(
    const int* __restrict__ w, const int* __restrict__ flag,
    int* __restrict__ gcount, int* __restrict__ blkbase) {
  __shared__ int h[NBKT];
  const int t = threadIdx.x, b = blockIdx.x;
  for (int i = t; i < NBKT; i += 256) h[i] = 0;
  __syncthreads();
  const int i64 = flag[0];
  const int pEnd = (b + 1) * PAIRS_PER_BLK;
  for (int p = b * PAIRS_PER_BLK + t; p < pEnd; p += 256) {
    int d0, d1;
    if (i64) {
      const int4 vd = *(const int4*)(w + 2 * (size_t)N_EDGES + 4 * (size_t)p);
      d0 = vd.x; d1 = vd.z;
    } else {
      const int2 vd = *(const int2*)(w + (size_t)N_EDGES + 2 * (size_t)p);
      d0 = vd.x; d1 = vd.y;
    }
    atomicAdd(&h[d0 >> 7], 1);
    atomicAdd(&h[d1 >> 7], 1);
  }
  __syncthreads();
  for (int i = t; i < NBKT; i += 256)
    blkbase[b * NBKT + i] = atomicAdd(&gcount[i], h[i]);  // coalesced
}

// ---------- Phase B: single-block exclusive scan of 782 bucket counts -------
__global__ __launch_bounds__(256) void part_scan(
    const int* __restrict__ gcount, int* __restrict__ gbase) {
  __shared__ int lds[256];
  const int t = threadIdx.x;
  int v[4];
  int s = 0;
#pragma unroll
  for (int j = 0; j < 4; ++j) {
    const int idx = t * 4 + j;
    v[j] = (idx < NBKT) ? gcount[idx] : 0;
    s += v[j];
  }
  lds[t] = s;
  __syncthreads();
  for (int o = 1; o < 256; o <<= 1) {
    const int val = (t >= o) ? lds[t - o] : 0;
    __syncthreads();
    lds[t] += val;
    __syncthreads();
  }
  int run = lds[t] - s;
#pragma unroll
  for (int j = 0; j < 4; ++j) {
    const int idx = t * 4 + j;
    if (idx < NBKT) gbase[idx] = run;
    run += v[j];
  }
}

// ---------- Phase C: scatter edges into coarse-bucket regions (LDS cursors) -
__global__ __launch_bounds__(256) void part_scatter(
    const int* __restrict__ w, const int* __restrict__ flag,
    const int* __restrict__ gbase, const int* __restrict__ blkbase,
    int2* __restrict__ pe) {
  __shared__ int cur[NBKT];
  const int t = threadIdx.x, b = blockIdx.x;
  for (int i = t; i < NBKT; i += 256)
    cur[i] = gbase[i] + blkbase[b * NBKT + i];
  __syncthreads();
  const int i64 = flag[0];
  const int pEnd = (b + 1) * PAIRS_PER_BLK;
  for (int p = b * PAIRS_PER_BLK + t; p < pEnd; p += 256) {
    int s0, s1, d0, d1;
    if (i64) {
      const int4 vs = *(const int4*)(w + 4 * (size_t)p);
      const int4 vd = *(const int4*)(w + 2 * (size_t)N_EDGES + 4 * (size_t)p);
      s0 = vs.x; s1 = vs.z;
      d0 = vd.x; d1 = vd.z;
    } else {
      const int2 vs = *(const int2*)(w + 2 * (size_t)p);
      const int2 vd = *(const int2*)(w + (size_t)N_EDGES + 2 * (size_t)p);
      s0 = vs.x; s1 = vs.y;
      d0 = vd.x; d1 = vd.y;
    }
    const int sl0 = atomicAdd(&cur[d0 >> 7], 1);
    pe[sl0] = make_int2(s0, d0);
    const int sl1 = atomicAdd(&cur[d1 >> 7], 1);
    pe[sl1] = make_int2(s1, d1);
  }
}

// ---------- Phase D: per-bucket CSR build entirely in LDS -------------------
__global__ __launch_bounds__(256) void bucket_csr(
    const int2* __restrict__ pe, const int* __restrict__ gbase,
    const int* __restrict__ gcount, int* __restrict__ deg,
    int* __restrict__ off, int* __restrict__ sortedSrc) {
  __shared__ int ldeg[128];
  __shared__ int loff[128];
  __shared__ int lcur[128];
  const int t = threadIdx.x;
  const int bkt = blockIdx.x;
  const int nbase = bkt << 7;
  const int ebase = gbase[bkt];
  const int cnt = gcount[bkt];
  if (t < 128) ldeg[t] = 0;
  __syncthreads();
  for (int e = t; e < cnt; e += 256) {
    const int2 sd = pe[ebase + e];
    atomicAdd(&ldeg[sd.y - nbase], 1);
  }
  __syncthreads();
  if (t < 128) loff[t] = ldeg[t];
  __syncthreads();
  for (int o = 1; o < 128; o <<= 1) {
    int v = 0;
    if (t >= o && t < 128) v = loff[t - o];
    __syncthreads();
    if (t < 128) loff[t] += v;
    __syncthreads();
  }
  if (t < 128) {
    const int ex = loff[t] - ldeg[t];
    lcur[t] = ex;
    const int n = nbase + t;
    if (n < N_NODES) {
      deg[n] = ldeg[t];
      off[n] = ebase + ex;
    }
  }
  __syncthreads();
  for (int e = t; e < cnt; e += 256) {
    const int2 sd = pe[ebase + e];
    const int p = atomicAdd(&lcur[sd.y - nbase], 1);
    sortedSrc[ebase + p] = sd.x;
  }
}

// ------- Layer 0 MFMA GEMM: [p0 | s0b] = x @ [Wneigh0 | Wself0] (+b0) -------
__global__ __launch_bounds__(256) void gemm0(
    const float* __restrict__ x, const unsigned short* __restrict__ B0h,
    const unsigned short* __restrict__ B0l, const float* __restrict__ b0,
    unsigned short* __restrict__ p0u, float* __restrict__ s0b) {
  __shared__ unsigned short lbh[128 * 128];
  __shared__ unsigned short lbl[128 * 128];
  const int tid = threadIdx.x;
  {
    const uint4* gh = (const uint4*)B0h;
    const uint4* gl = (const uint4*)B0l;
    for (int i = tid; i < 2048; i += 256) {
      const int o = i << 4;
      const int sw = o ^ (((o >> 8) & 7) << 4);
      *(uint4*)((char*)lbh + sw) = gh[i];
      *(uint4*)((char*)lbl + sw) = gl[i];
    }
  }
  __syncthreads();
  const int lane = tid & 63;
  const int wave = tid >> 6;
  const int rowbase = blockIdx.x * 64 + wave * 16;
  const int arow = rowbase + (lane & 15);
  const int rclamp = (arow < N_NODES) ? arow : 0;
  const int ko = (lane >> 4) << 3;

  f32x4 acc[8];
#pragma unroll
  for (int ct = 0; ct < 8; ++ct) acc[ct] = (f32x4){0.f, 0.f, 0.f, 0.f};

  for (int ks = 0; ks < 4; ++ks) {
    float av[8];
    const float* ax = x + (size_t)rclamp * IN_DIM + ks * 32 + ko;
    *(float4*)&av[0] = *(const float4*)ax;
    *(float4*)&av[4] = *(const float4*)(ax + 4);
    short8 ah, al;
#pragma unroll
    for (int j = 0; j < 8; ++j) {
      const unsigned short hi = bf16rne(av[j]);
      ah[j] = (short)hi;
      al[j] = (short)bf16rne(av[j] - uf(hi));
    }
    const int kb = ks * 64 + (ko << 1);
#pragma unroll
    for (int ct = 0; ct < 8; ++ct) {
      const int n = ct * 16 + (lane & 15);
      const int boff = (n << 8) + kb;
      const int sb = boff ^ (((boff >> 8) & 7) << 4);
      const short8 bh = *(const short8*)((const char*)lbh + sb);
      const short8 bl = *(const short8*)((const char*)lbl + sb);
      acc[ct] = __builtin_amdgcn_mfma_f32_16x16x32_bf16(ah, bh, acc[ct], 0, 0, 0);
      acc[ct] = __builtin_amdgcn_mfma_f32_16x16x32_bf16(ah, bl, acc[ct], 0, 0, 0);
      acc[ct] = __builtin_amdgcn_mfma_f32_16x16x32_bf16(al, bh, acc[ct], 0, 0, 0);
    }
  }
  const int rb4 = rowbase + ((lane >> 4) << 2);
  const int cc = lane & 15;
#pragma unroll
  for (int ct = 0; ct < 4; ++ct) {
#pragma unroll
    for (int j = 0; j < 4; ++j) {
      const int r = rb4 + j;
      if (r < N_NODES) p0u[(size_t)r * HID + ct * 16 + cc] = bf16rne(acc[ct][j]);
    }
  }
#pragma unroll
  for (int ct = 4; ct < 8; ++ct) {
    const float bias = b0[(ct - 4) * 16 + cc];
#pragma unroll
    for (int j = 0; j < 4; ++j) {
      const int r = rb4 + j;
      if (r < N_NODES) s0b[(size_t)r * HID + (ct - 4) * 16 + cc] = acc[ct][j] + bias;
    }
  }
}

// ------- Layer 1 MFMA GEMM: [p1 | s1b] = h1 @ [Wneigh1 | Wself1] (+b1) ------
__global__ __launch_bounds__(256) void gemm1(
    const float* __restrict__ h1, const unsigned short* __restrict__ B1h,
    const unsigned short* __restrict__ B1l, const float* __restrict__ b1,
    unsigned short* __restrict__ p1u, float* __restrict__ s1b) {
  __shared__ unsigned short lbh[64 * 64];
  __shared__ unsigned short lbl[64 * 64];
  const int tid = threadIdx.x;
  {
    const uint4* gh = (const uint4*)B1h;
    const uint4* gl = (const uint4*)B1l;
    for (int i = tid; i < 512; i += 256) {
      const int o = i << 4;
      const int sw = o ^ (((o >> 7) & 7) << 4);
      *(uint4*)((char*)lbh + sw) = gh[i];
      *(uint4*)((char*)lbl + sw) = gl[i];
    }
  }
  __syncthreads();
  const int lane = tid & 63;
  const int wave = tid >> 6;
  const int rowbase = blockIdx.x * 64 + wave * 16;
  const int arow = rowbase + (lane & 15);
  const int rclamp = (arow < N_NODES) ? arow : 0;
  const int ko = (lane >> 4) << 3;

  f32x4 acc[4];
#pragma unroll
  for (int ct = 0; ct < 4; ++ct) acc[ct] = (f32x4){0.f, 0.f, 0.f, 0.f};

  for (int ks = 0; ks < 2; ++ks) {
    float av[8];
    const float* ax = h1 + (size_t)rclamp * HID + ks * 32 + ko;
    *(float4*)&av[0] = *(const float4*)ax;
    *(float4*)&av[4] = *(const float4*)(ax + 4);
    short8 ah, al;
#pragma unroll
    for (int j = 0; j < 8; ++j) {
      const unsigned short hi = bf16rne(av[j]);
      ah[j] = (short)hi;
      al[j] = (short)bf16rne(av[j] - uf(hi));
    }
    const int kb = ks * 64 + (ko << 1);
#pragma unroll
    for (int ct = 0; ct < 4; ++ct) {
      const int n = ct * 16 + (lane & 15);
      const int boff = (n << 7) + kb;
      const int sb = boff ^ (((boff >> 7) & 7) << 4);
      const short8 bh = *(const short8*)((const char*)lbh + sb);
      const short8 bl = *(const short8*)((const char*)lbl + sb);
      acc[ct] = __builtin_amdgcn_mfma_f32_16x16x32_bf16(ah, bh, acc[ct], 0, 0, 0);
      acc[ct] = __builtin_amdgcn_mfma_f32_16x16x32_bf16(ah, bl, acc[ct], 0, 0, 0);
      acc[ct] = __builtin_amdgcn_mfma_f32_16x16x32_bf16(al, bh, acc[ct], 0, 0, 0);
    }
  }
  const int rb4 = rowbase + ((lane >> 4) << 2);
  const int cc = lane & 15;
#pragma unroll
  for (int ct = 0; ct < 2; ++ct) {
#pragma unroll
    for (int j = 0; j < 4; ++j) {
      const int r = rb4 + j;
      if (r < N_NODES) p1u[(size_t)r * OUT_DIM + ct * 16 + cc] = bf16rne(acc[ct][j]);
    }
  }
#pragma unroll
  for (int ct = 2; ct < 4; ++ct) {
    const float bias = b1[(ct - 2) * 16 + cc];
#pragma unroll
    for (int j = 0; j < 4; ++j) {
      const int r = rb4 + j;
      if (r < N_NODES)
        s1b[(size_t)r * OUT_DIM + (ct - 2) * 16 + cc] = acc[ct][j] + bias;
    }
  }
}

// ------- Fused layer-0 aggregate + mean + LN + ReLU -> h1 -------------------
__global__ __launch_bounds__(256) void aggc0(
    const int* __restrict__ sortedSrc, const int* __restrict__ off,
    const int* __restrict__ deg, const unsigned short* __restrict__ p0u,
    const float* __restrict__ s0b, const float* __restrict__ g,
    const float* __restrict__ be, float* __restrict__ h1) {
  const int lane = threadIdx.x & 63;
  const int grp = lane >> 3;
  const int sl = lane & 7;
  const int i = blockIdx.x * 4 + (threadIdx.x >> 6);
  if (i >= N_NODES) return;
  const int st = off[i];
  const int dg = deg[i];
  float acc[8];
#pragma unroll
  for (int f = 0; f < 8; ++f) acc[f] = 0.f;

  for (int base = 0; base < dg; base += 64) {
    const int cnt = min(64, dg - base);
    const int idx = (lane < cnt) ? sortedSrc[st + base + lane] : 0;
    for (int j = 0; j * 8 < cnt; ++j) {
      const int e = j * 8 + grp;
      const float msk = (e < cnt) ? 1.f : 0.f;
      const int srcn = __shfl(idx, min(e, cnt - 1));
      const uint4 q = *(const uint4*)(p0u + (size_t)srcn * HID + sl * 8);
      acc[0] = fmaf(msk, uflo(q.x), acc[0]);
      acc[1] = fmaf(msk, ufhi(q.x), acc[1]);
      acc[2] = fmaf(msk, uflo(q.y), acc[2]);
      acc[3] = fmaf(msk, ufhi(q.y), acc[3]);
      acc[4] = fmaf(msk, uflo(q.z), acc[4]);
      acc[5] = fmaf(msk, ufhi(q.z), acc[5]);
      acc[6] = fmaf(msk, uflo(q.w), acc[6]);
      acc[7] = fmaf(msk, ufhi(q.w), acc[7]);
    }
  }
#pragma unroll
  for (int mk = 8; mk < 64; mk <<= 1) {
#pragma unroll
    for (int f = 0; f < 8; ++f) acc[f] += __shfl_xor(acc[f], mk);
  }
  const float inv = 1.0f / fmaxf((float)dg, 1.0f);
  float z[8];
  const float4 sb0 = *(const float4*)(s0b + (size_t)i * HID + sl * 8);
  const float4 sb1 = *(const float4*)(s0b + (size_t)i * HID + sl * 8 + 4);
  z[0] = sb0.x + acc[0] * inv; z[1] = sb0.y + acc[1] * inv;
  z[2] = sb0.z + acc[2] * inv; z[3] = sb0.w + acc[3] * inv;
  z[4] = sb1.x + acc[4] * inv; z[5] = sb1.y + acc[5] * inv;
  z[6] = sb1.z + acc[6] * inv; z[7] = sb1.w + acc[7] * inv;
  float pm = 0.f;
#pragma unroll
  for (int f = 0; f < 8; ++f) pm += z[f];
#pragma unroll
  for (int mk = 1; mk < 8; mk <<= 1) pm += __shfl_xor(pm, mk);
  const float mean = pm * (1.0f / 64.0f);
  float pv = 0.f;
#pragma unroll
  for (int f = 0; f < 8; ++f) {
    z[f] -= mean;
    pv += z[f] * z[f];
  }
#pragma unroll
  for (int mk = 1; mk < 8; mk <<= 1) pv += __shfl_xor(pv, mk);
  const float rstd = rsqrtf(pv * (1.0f / 64.0f) + LN_EPS);
  if (grp == 0) {
    const float4 gv0 = *(const float4*)(g + sl * 8);
    const float4 gv1 = *(const float4*)(g + sl * 8 + 4);
    const float4 bv0 = *(const float4*)(be + sl * 8);
    const float4 bv1 = *(const float4*)(be + sl * 8 + 4);
    float4 o0, o1;
    o0.x = fmaxf(z[0] * rstd * gv0.x + bv0.x, 0.f);
    o0.y = fmaxf(z[1] * rstd * gv0.y + bv0.y, 0.f);
    o0.z = fmaxf(z[2] * rstd * gv0.z + bv0.z, 0.f);
    o0.w = fmaxf(z[3] * rstd * gv0.w + bv0.w, 0.f);
    o1.x = fmaxf(z[4] * rstd * gv1.x + bv1.x, 0.f);
    o1.y = fmaxf(z[5] * rstd * gv1.y + bv1.y, 0.f);
    o1.z = fmaxf(z[6] * rstd * gv1.z + bv1.z, 0.f);
    o1.w = fmaxf(z[7] * rstd * gv1.w + bv1.w, 0.f);
    *(float4*)(h1 + (size_t)i * HID + sl * 8) = o0;
    *(float4*)(h1 + (size_t)i * HID + sl * 8 + 4) = o1;
  }
}

// ------- Fused layer-1 aggregate + mean + LN + ReLU -> out ------------------
__global__ __launch_bounds__(256) void aggc1(
    const int* __restrict__ sortedSrc, const int* __restrict__ off,
    const int* __restrict__ deg, const unsigned short* __restrict__ p1u,
    const float* __restrict__ s1b, const float* __restrict__ g,
    const float* __restrict__ be, float* __restrict__ out) {
  const int lane = threadIdx.x & 63;
  const int grp = lane >> 2;
  const int sl = lane & 3;
  const int i = blockIdx.x * 4 + (threadIdx.x >> 6);
  if (i >= N_NODES) return;
  const int st = off[i];
  const int dg = deg[i];
  float acc[8];
#pragma unroll
  for (int f = 0; f < 8; ++f) acc[f] = 0.f;

  for (int base = 0; base < dg; base += 64) {
    const int cnt = min(64, dg - base);
    const int idx = (lane < cnt) ? sortedSrc[st + base + lane] : 0;
    for (int j = 0; j * 16 < cnt; ++j) {
      const int e = j * 16 + grp;
      const float msk = (e < cnt) ? 1.f : 0.f;
      const int srcn = __shfl(idx, min(e, cnt - 1));
      const uint4 q = *(const uint4*)(p1u + (size_t)srcn * OUT_DIM + sl * 8);
      acc[0] = fmaf(msk, uflo(q.x), acc[0]);
      acc[1] = fmaf(msk, ufhi(q.x), acc[1]);
      acc[2] = fmaf(msk, uflo(q.y), acc[2]);
      acc[3] = fmaf(msk, ufhi(q.y), acc[3]);
      acc[4] = fmaf(msk, uflo(q.z), acc[4]);
      acc[5] = fmaf(msk, ufhi(q.z), acc[5]);
      acc[6] = fmaf(msk, uflo(q.w), acc[6]);
      acc[7] = fmaf(msk, ufhi(q.w), acc[7]);
    }
  }
#pragma unroll
  for (int mk = 4; mk < 64; mk <<= 1) {
#pragma unroll
    for (int f = 0; f < 8; ++f) acc[f] += __shfl_xor(acc[f], mk);
  }
  const float inv = 1.0f / fmaxf((float)dg, 1.0f);
  float z[8];
  const float4 sb0 = *(const float4*)(s1b + (size_t)i * OUT_DIM + sl * 8);
  const float4 sb1 = *(const float4*)(s1b + (size_t)i * OUT_DIM + sl * 8 + 4);
  z[0] = sb0.x + acc[0] * inv; z[1] = sb0.y + acc[1] * inv;
  z[2] = sb0.z + acc[2] * inv; z[3] = sb0.w + acc[3] * inv;
  z[4] = sb1.x + acc[4] * inv; z[5] = sb1.y + acc[5] * inv;
  z[6] = sb1.z + acc[6] * inv; z[7] = sb1.w + acc[7] * inv;
  float pm = 0.f;
#pragma unroll
  for (int f = 0; f < 8; ++f) pm += z[f];
#pragma unroll
  for (int mk = 1; mk < 4; mk <<= 1) pm += __shfl_xor(pm, mk);
  const float mean = pm * (1.0f / 32.0f);
  float pv = 0.f;
#pragma unroll
  for (int f = 0; f < 8; ++f) {
    z[f] -= mean;
    pv += z[f] * z[f];
  }
#pragma unroll
  for (int mk = 1; mk < 4; mk <<= 1) pv += __shfl_xor(pv, mk);
  const float rstd = rsqrtf(pv * (1.0f / 32.0f) + LN_EPS);
  if (grp == 0) {
    const float4 gv0 = *(const float4*)(g + sl * 8);
    const float4 gv1 = *(const float4*)(g + sl * 8 + 4);
    const float4 bv0 = *(const float4*)(be + sl * 8);
    const float4 bv1 = *(const float4*)(be + sl * 8 + 4);
    float4 o0, o1;
    o0.x = fmaxf(z[0] * rstd * gv0.x + bv0.x, 0.f);
    o0.y = fmaxf(z[1] * rstd * gv0.y + bv0.y, 0.f);
    o0.z = fmaxf(z[2] * rstd * gv0.z + bv0.z, 0.f);
    o0.w = fmaxf(z[3] * rstd * gv0.w + bv0.w, 0.f);
    o1.x = fmaxf(z[4] * rstd * gv1.x + bv1.x, 0.f);
    o1.y = fmaxf(z[5] * rstd * gv1.y + bv1.y, 0.f);
    o1.z = fmaxf(z[6] * rstd * gv1.z + bv1.z, 0.f);
    o1.w = fmaxf(z[7] * rstd * gv1.w + bv1.w, 0.f);
    *(float4*)(out + (size_t)i * OUT_DIM + sl * 8) = o0;
    *(float4*)(out + (size_t)i * OUT_DIM + sl * 8 + 4) = o1;
  }
}

extern "C" void kernel_launch(void* const* d_in, const int* in_sizes, int n_in,
                              void* d_out, int out_size, void* d_ws, size_t ws_size,
                              hipStream_t stream) {
  const float* x       = (const float*)d_in[0];
  const int*   edges   = (const int*)d_in[1];
  const float* Wself0  = (const float*)d_in[2];
  const float* Wneigh0 = (const float*)d_in[3];
  const float* b0      = (const float*)d_in[4];
  const float* g0      = (const float*)d_in[5];
  const float* be0     = (const float*)d_in[6];
  const float* Wself1  = (const float*)d_in[7];
  const float* Wneigh1 = (const float*)d_in[8];
  const float* b1      = (const float*)d_in[9];
  const float* g1      = (const float*)d_in[10];
  const float* be1     = (const float*)d_in[11];

  int* flag      = (int*)d_ws;                    // 64
  int* gcount    = flag + 64;                     // 1024 (padded)
  int* gbase     = gcount + 1024;                 // 1024 (padded)
  int* blkbase   = gbase + 1024;                  // NPBLK*NBKT = 391000
  int* deg       = blkbase + 400000;              // 100000
  int* off       = deg + N_NODES;                 // 100000
  int* sortedSrc = off + N_NODES;                 // 1.6M
  int2* pe       = (int2*)(sortedSrc + N_EDGES);  // 1.6M int2
  unsigned short* B0h = (unsigned short*)(pe + N_EDGES);
  unsigned short* B0l = B0h + 128 * 128;
  unsigned short* B1h = B0l + 128 * 128;
  unsigned short* B1l = B1h + 64 * 64;
  unsigned short* p0u = B1l + 64 * 64;
  float* s0b = (float*)(p0u + (size_t)N_NODES * HID);
  float* h1  = s0b + (size_t)N_NODES * HID;
  unsigned short* p1u = p0u;  // overlay (p0 dead)
  float* s1b = s0b;           // overlay (s0b dead)

  hipMemsetAsync(gcount, 0, NBKT * sizeof(int), stream);

  detect_edges<<<1, 256, 0, stream>>>(edges, flag);
  convW<<<80, 256, 0, stream>>>(Wneigh0, Wself0, Wneigh1, Wself1,
                                B0h, B0l, B1h, B1l);
  part_count<<<NPBLK, 256, 0, stream>>>(edges, flag, gcount, blkbase);
  part_scan<<<1, 256, 0, stream>>>(gcount, gbase);
  part_scatter<<<NPBLK, 256, 0, stream>>>(edges, flag, gbase, blkbase, pe);
  bucket_csr<<<NBKT, 256, 0, stream>>>(pe, gbase, gcount, deg, off, sortedSrc);

  gemm0<<<(N_NODES + 63) / 64, 256, 0, stream>>>(x, B0h, B0l, b0, p0u, s0b);
  aggc0<<<(N_NODES + 3) / 4, 256, 0, stream>>>(sortedSrc, off, deg, p0u, s0b,
                                               g0, be0, h1);
  gemm1<<<(N_NODES + 63) / 64, 256, 0, stream>>>(h1, B1h, B1l, b1, p1u, s1b);
  aggc1<<<(N_NODES + 3) / 4, 256, 0, stream>>>(sortedSrc, off, deg, p1u, s1b,
                                               g1, be1, (float*)d_out);
}

// Round 8
// 174.895 us; speedup vs baseline: 4.2153x; 1.1861x over previous
//
#include <hip/hip_runtime.h>
#include <hip/hip_bf16.h>

#define N_NODES 100000
#define N_EDGES 1600000
#define IN_DIM 128
#define HID 64
#define OUT_DIM 32
#define LN_EPS 1e-5f
#define NBKT 782            // ceil(100000/128) coarse buckets (128 nodes each)
#define NPBLK 500           // partition blocks
#define PAIRS_PER_BLK 1600  // 500*1600*2 = 1.6M edges
#define G0BLK 1563          // gemm0 blocks: ceil(100000/64)

typedef __attribute__((ext_vector_type(8))) short short8;
typedef __attribute__((ext_vector_type(4))) float f32x4;

__device__ __forceinline__ float uf(unsigned short u) {
  return __uint_as_float(((unsigned int)u) << 16);
}
__device__ __forceinline__ float uflo(unsigned int u) {
  return __uint_as_float(u << 16);
}
__device__ __forceinline__ float ufhi(unsigned int u) {
  return __uint_as_float(u & 0xffff0000u);
}
__device__ __forceinline__ unsigned short bf16rne(float f) {
  unsigned int u = __float_as_uint(f);
  unsigned int r = u + 0x7fffu + ((u >> 16) & 1u);
  return (unsigned short)(r >> 16);
}

// ---------- Edge dtype detect: int64 (high words all 0) vs int32 ------------
__global__ void detect_edges(const int* __restrict__ w, int* __restrict__ flag) {
  __shared__ int any;
  if (threadIdx.x == 0) any = 0;
  __syncthreads();
  if (w[2 * threadIdx.x + 1] != 0) any = 1;
  __syncthreads();
  if (threadIdx.x == 0) flag[0] = any ? 0 : 1;  // 1 => int64 layout
}

// ---------- Weight split: B0 [128n][128k] hi/lo, B1 [64n][64k] hi/lo --------
__global__ __launch_bounds__(256) void convW(
    const float* __restrict__ Wn0, const float* __restrict__ Ws0,
    const float* __restrict__ Wn1, const float* __restrict__ Ws1,
    unsigned short* __restrict__ B0h, unsigned short* __restrict__ B0l,
    unsigned short* __restrict__ B1h, unsigned short* __restrict__ B1l) {
  const int i = blockIdx.x * 256 + threadIdx.x;
  if (i < 128 * 128) {
    const int n = i >> 7, k = i & 127;
    const float w = (n < 64) ? Wn0[k * 64 + n] : Ws0[k * 64 + (n - 64)];
    const unsigned short hi = bf16rne(w);
    B0h[i] = hi;
    B0l[i] = bf16rne(w - uf(hi));
  } else if (i < 128 * 128 + 64 * 64) {
    const int j = i - 128 * 128;
    const int n = j >> 6, k = j & 63;
    const float w = (n < 32) ? Wn1[k * 32 + n] : Ws1[k * 32 + (n - 32)];
    const unsigned short hi = bf16rne(w);
    B1h[j] = hi;
    B1l[j] = bf16rne(w - uf(hi));
  }
}

// ---------- FUSED: part_count (blocks 0..499) || gemm0 (blocks 500..2062) ---
// part_count: coarse histogram + coalesced reservation (uses lbh as scratch).
// gemm0: [p0 | s0b] = x @ [Wneigh0 | Wself0] (+b0), split-bf16 MFMA.
__global__ __launch_bounds__(256) void g0pc(
    const float* __restrict__ x, const unsigned short* __restrict__ B0h,
    const unsigned short* __restrict__ B0l, const float* __restrict__ b0,
    unsigned short* __restrict__ p0u, float* __restrict__ s0b,
    const int* __restrict__ w, const int* __restrict__ flag,
    int* __restrict__ gcount, int* __restrict__ blkbase) {
  __shared__ unsigned short lbh[128 * 128];  // 32 KB (pc: int hist scratch)
  __shared__ unsigned short lbl[128 * 128];  // 32 KB
  const int tid = threadIdx.x;

  if (blockIdx.x < NPBLK) {
    // ---------------- part_count path ----------------
    int* h = (int*)lbh;
    const int b = blockIdx.x;
    for (int i = tid; i < NBKT; i += 256) h[i] = 0;
    __syncthreads();
    const int i64 = flag[0];
    const int pEnd = (b + 1) * PAIRS_PER_BLK;
    for (int p = b * PAIRS_PER_BLK + tid; p < pEnd; p += 256) {
      int d0, d1;
      if (i64) {
        const int4 vd = *(const int4*)(w + 2 * (size_t)N_EDGES + 4 * (size_t)p);
        d0 = vd.x; d1 = vd.z;
      } else {
        const int2 vd = *(const int2*)(w + (size_t)N_EDGES + 2 * (size_t)p);
        d0 = vd.x; d1 = vd.y;
      }
      atomicAdd(&h[d0 >> 7], 1);
      atomicAdd(&h[d1 >> 7], 1);
    }
    __syncthreads();
    for (int i = tid; i < NBKT; i += 256)
      blkbase[b * NBKT + i] = atomicAdd(&gcount[i], h[i]);  // coalesced
    return;
  }

  // ---------------- gemm0 path ----------------
  {
    const uint4* gh = (const uint4*)B0h;
    const uint4* gl = (const uint4*)B0l;
    for (int i = tid; i < 2048; i += 256) {
      const int o = i << 4;
      const int sw = o ^ (((o >> 8) & 7) << 4);
      *(uint4*)((char*)lbh + sw) = gh[i];
      *(uint4*)((char*)lbl + sw) = gl[i];
    }
  }
  __syncthreads();
  const int lane = tid & 63;
  const int wave = tid >> 6;
  const int rowbase = (blockIdx.x - NPBLK) * 64 + wave * 16;
  const int arow = rowbase + (lane & 15);
  const int rclamp = (arow < N_NODES) ? arow : 0;
  const int ko = (lane >> 4) << 3;

  f32x4 acc[8];
#pragma unroll
  for (int ct = 0; ct < 8; ++ct) acc[ct] = (f32x4){0.f, 0.f, 0.f, 0.f};

  for (int ks = 0; ks < 4; ++ks) {
    float av[8];
    const float* ax = x + (size_t)rclamp * IN_DIM + ks * 32 + ko;
    *(float4*)&av[0] = *(const float4*)ax;
    *(float4*)&av[4] = *(const float4*)(ax + 4);
    short8 ah, al;
#pragma unroll
    for (int j = 0; j < 8; ++j) {
      const unsigned short hi = bf16rne(av[j]);
      ah[j] = (short)hi;
      al[j] = (short)bf16rne(av[j] - uf(hi));
    }
    const int kb = ks * 64 + (ko << 1);
#pragma unroll
    for (int ct = 0; ct < 8; ++ct) {
      const int n = ct * 16 + (lane & 15);
      const int boff = (n << 8) + kb;
      const int sb = boff ^ (((boff >> 8) & 7) << 4);
      const short8 bh = *(const short8*)((const char*)lbh + sb);
      const short8 bl = *(const short8*)((const char*)lbl + sb);
      acc[ct] = __builtin_amdgcn_mfma_f32_16x16x32_bf16(ah, bh, acc[ct], 0, 0, 0);
      acc[ct] = __builtin_amdgcn_mfma_f32_16x16x32_bf16(ah, bl, acc[ct], 0, 0, 0);
      acc[ct] = __builtin_amdgcn_mfma_f32_16x16x32_bf16(al, bh, acc[ct], 0, 0, 0);
    }
  }
  const int rb4 = rowbase + ((lane >> 4) << 2);
  const int cc = lane & 15;
#pragma unroll
  for (int ct = 0; ct < 4; ++ct) {
#pragma unroll
    for (int j = 0; j < 4; ++j) {
      const int r = rb4 + j;
      if (r < N_NODES) p0u[(size_t)r * HID + ct * 16 + cc] = bf16rne(acc[ct][j]);
    }
  }
#pragma unroll
  for (int ct = 4; ct < 8; ++ct) {
    const float bias = b0[(ct - 4) * 16 + cc];
#pragma unroll
    for (int j = 0; j < 4; ++j) {
      const int r = rb4 + j;
      if (r < N_NODES) s0b[(size_t)r * HID + (ct - 4) * 16 + cc] = acc[ct][j] + bias;
    }
  }
}

// ---------- Phase B: single-block exclusive scan of 782 bucket counts -------
__global__ __launch_bounds__(256) void part_scan(
    const int* __restrict__ gcount, int* __restrict__ gbase) {
  __shared__ int lds[256];
  const int t = threadIdx.x;
  int v[4];
  int s = 0;
#pragma unroll
  for (int j = 0; j < 4; ++j) {
    const int idx = t * 4 + j;
    v[j] = (idx < NBKT) ? gcount[idx] : 0;
    s += v[j];
  }
  lds[t] = s;
  __syncthreads();
  for (int o = 1; o < 256; o <<= 1) {
    const int val = (t >= o) ? lds[t - o] : 0;
    __syncthreads();
    lds[t] += val;
    __syncthreads();
  }
  int run = lds[t] - s;
#pragma unroll
  for (int j = 0; j < 4; ++j) {
    const int idx = t * 4 + j;
    if (idx < NBKT) gbase[idx] = run;
    run += v[j];
  }
}

// ---------- Phase C: scatter edges into coarse-bucket regions (LDS cursors) -
__global__ __launch_bounds__(256) void part_scatter(
    const int* __restrict__ w, const int* __restrict__ flag,
    const int* __restrict__ gbase, const int* __restrict__ blkbase,
    int2* __restrict__ pe) {
  __shared__ int cur[NBKT];
  const int t = threadIdx.x, b = blockIdx.x;
  for (int i = t; i < NBKT; i += 256)
    cur[i] = gbase[i] + blkbase[b * NBKT + i];
  __syncthreads();
  const int i64 = flag[0];
  const int pEnd = (b + 1) * PAIRS_PER_BLK;
  for (int p = b * PAIRS_PER_BLK + t; p < pEnd; p += 256) {
    int s0, s1, d0, d1;
    if (i64) {
      const int4 vs = *(const int4*)(w + 4 * (size_t)p);
      const int4 vd = *(const int4*)(w + 2 * (size_t)N_EDGES + 4 * (size_t)p);
      s0 = vs.x; s1 = vs.z;
      d0 = vd.x; d1 = vd.z;
    } else {
      const int2 vs = *(const int2*)(w + 2 * (size_t)p);
      const int2 vd = *(const int2*)(w + (size_t)N_EDGES + 2 * (size_t)p);
      s0 = vs.x; s1 = vs.y;
      d0 = vd.x; d1 = vd.y;
    }
    const int sl0 = atomicAdd(&cur[d0 >> 7], 1);
    pe[sl0] = make_int2(s0, d0);
    const int sl1 = atomicAdd(&cur[d1 >> 7], 1);
    pe[sl1] = make_int2(s1, d1);
  }
}

// ---------- Phase D: per-bucket CSR build entirely in LDS -------------------
__global__ __launch_bounds__(256) void bucket_csr(
    const int2* __restrict__ pe, const int* __restrict__ gbase,
    const int* __restrict__ gcount, int* __restrict__ deg,
    int* __restrict__ off, int* __restrict__ sortedSrc) {
  __shared__ int ldeg[128];
  __shared__ int loff[128];
  __shared__ int lcur[128];
  const int t = threadIdx.x;
  const int bkt = blockIdx.x;
  const int nbase = bkt << 7;
  const int ebase = gbase[bkt];
  const int cnt = gcount[bkt];
  if (t < 128) ldeg[t] = 0;
  __syncthreads();
  for (int e = t; e < cnt; e += 256) {
    const int2 sd = pe[ebase + e];
    atomicAdd(&ldeg[sd.y - nbase], 1);
  }
  __syncthreads();
  if (t < 128) loff[t] = ldeg[t];
  __syncthreads();
  for (int o = 1; o < 128; o <<= 1) {
    int v = 0;
    if (t >= o && t < 128) v = loff[t - o];
    __syncthreads();
    if (t < 128) loff[t] += v;
    __syncthreads();
  }
  if (t < 128) {
    const int ex = loff[t] - ldeg[t];
    lcur[t] = ex;
    const int n = nbase + t;
    if (n < N_NODES) {
      deg[n] = ldeg[t];
      off[n] = ebase + ex;
    }
  }
  __syncthreads();
  for (int e = t; e < cnt; e += 256) {
    const int2 sd = pe[ebase + e];
    const int p = atomicAdd(&lcur[sd.y - nbase], 1);
    sortedSrc[ebase + p] = sd.x;
  }
}

// ------- Layer 1 MFMA GEMM: [p1 | s1b] = h1 @ [Wneigh1 | Wself1] (+b1) ------
__global__ __launch_bounds__(256) void gemm1(
    const float* __restrict__ h1, const unsigned short* __restrict__ B1h,
    const unsigned short* __restrict__ B1l, const float* __restrict__ b1,
    unsigned short* __restrict__ p1u, float* __restrict__ s1b) {
  __shared__ unsigned short lbh[64 * 64];
  __shared__ unsigned short lbl[64 * 64];
  const int tid = threadIdx.x;
  {
    const uint4* gh = (const uint4*)B1h;
    const uint4* gl = (const uint4*)B1l;
    for (int i = tid; i < 512; i += 256) {
      const int o = i << 4;
      const int sw = o ^ (((o >> 7) & 7) << 4);
      *(uint4*)((char*)lbh + sw) = gh[i];
      *(uint4*)((char*)lbl + sw) = gl[i];
    }
  }
  __syncthreads();
  const int lane = tid & 63;
  const int wave = tid >> 6;
  const int rowbase = blockIdx.x * 64 + wave * 16;
  const int arow = rowbase + (lane & 15);
  const int rclamp = (arow < N_NODES) ? arow : 0;
  const int ko = (lane >> 4) << 3;

  f32x4 acc[4];
#pragma unroll
  for (int ct = 0; ct < 4; ++ct) acc[ct] = (f32x4){0.f, 0.f, 0.f, 0.f};

  for (int ks = 0; ks < 2; ++ks) {
    float av[8];
    const float* ax = h1 + (size_t)rclamp * HID + ks * 32 + ko;
    *(float4*)&av[0] = *(const float4*)ax;
    *(float4*)&av[4] = *(const float4*)(ax + 4);
    short8 ah, al;
#pragma unroll
    for (int j = 0; j < 8; ++j) {
      const unsigned short hi = bf16rne(av[j]);
      ah[j] = (short)hi;
      al[j] = (short)bf16rne(av[j] - uf(hi));
    }
    const int kb = ks * 64 + (ko << 1);
#pragma unroll
    for (int ct = 0; ct < 4; ++ct) {
      const int n = ct * 16 + (lane & 15);
      const int boff = (n << 7) + kb;
      const int sb = boff ^ (((boff >> 7) & 7) << 4);
      const short8 bh = *(const short8*)((const char*)lbh + sb);
      const short8 bl = *(const short8*)((const char*)lbl + sb);
      acc[ct] = __builtin_amdgcn_mfma_f32_16x16x32_bf16(ah, bh, acc[ct], 0, 0, 0);
      acc[ct] = __builtin_amdgcn_mfma_f32_16x16x32_bf16(ah, bl, acc[ct], 0, 0, 0);
      acc[ct] = __builtin_amdgcn_mfma_f32_16x16x32_bf16(al, bh, acc[ct], 0, 0, 0);
    }
  }
  const int rb4 = rowbase + ((lane >> 4) << 2);
  const int cc = lane & 15;
#pragma unroll
  for (int ct = 0; ct < 2; ++ct) {
#pragma unroll
    for (int j = 0; j < 4; ++j) {
      const int r = rb4 + j;
      if (r < N_NODES) p1u[(size_t)r * OUT_DIM + ct * 16 + cc] = bf16rne(acc[ct][j]);
    }
  }
#pragma unroll
  for (int ct = 2; ct < 4; ++ct) {
    const float bias = b1[(ct - 2) * 16 + cc];
#pragma unroll
    for (int j = 0; j < 4; ++j) {
      const int r = rb4 + j;
      if (r < N_NODES)
        s1b[(size_t)r * OUT_DIM + (ct - 2) * 16 + cc] = acc[ct][j] + bias;
    }
  }
}

// ------- Fused layer-0 aggregate + mean + LN + ReLU -> h1 (2 nodes/wave) ----
// lane = [h:1][grp:2][sl:3]; grid exact (no early return: shuffles wave-wide).
__global__ __launch_bounds__(256) void aggc0(
    const int* __restrict__ sortedSrc, const int* __restrict__ off,
    const int* __restrict__ deg, const unsigned short* __restrict__ p0u,
    const float* __restrict__ s0b, const float* __restrict__ g,
    const float* __restrict__ be, float* __restrict__ h1) {
  const int lane = threadIdx.x & 63;
  const int h = lane >> 5;          // node half
  const int grp = (lane >> 3) & 3;  // 4 edge groups
  const int sl = lane & 7;          // 8 feature slices
  const int i = blockIdx.x * 8 + ((threadIdx.x >> 6) << 1) + h;
  const int st = off[i];
  const int dg = deg[i];
  const int dgmax = max(dg, __shfl_xor(dg, 32));
  float acc[8];
#pragma unroll
  for (int f = 0; f < 8; ++f) acc[f] = 0.f;

  for (int base = 0; base < dgmax; base += 32) {
    const int cnt = min(32, dg - base);  // can be <= 0 for shorter node
    const int l5 = lane & 31;
    const int idx = (l5 < cnt) ? sortedSrc[st + base + l5] : 0;
    const int cntmax = min(32, dgmax - base);
    for (int j = 0; j * 4 < cntmax; ++j) {
      const int e = j * 4 + grp;
      const float msk = (e < cnt) ? 1.f : 0.f;
      const int es = max(min(e, cnt - 1), 0);
      const int srcn = __shfl(idx, (h << 5) | es);
      const uint4 q = *(const uint4*)(p0u + (size_t)srcn * HID + sl * 8);
      acc[0] = fmaf(msk, uflo(q.x), acc[0]);
      acc[1] = fmaf(msk, ufhi(q.x), acc[1]);
      acc[2] = fmaf(msk, uflo(q.y), acc[2]);
      acc[3] = fmaf(msk, ufhi(q.y), acc[3]);
      acc[4] = fmaf(msk, uflo(q.z), acc[4]);
      acc[5] = fmaf(msk, ufhi(q.z), acc[5]);
      acc[6] = fmaf(msk, uflo(q.w), acc[6]);
      acc[7] = fmaf(msk, ufhi(q.w), acc[7]);
    }
  }
  // fold edge groups (xor over lane bits 3,4 — stays within node half)
#pragma unroll
  for (int mk = 8; mk < 32; mk <<= 1) {
#pragma unroll
    for (int f = 0; f < 8; ++f) acc[f] += __shfl_xor(acc[f], mk);
  }
  const float inv = 1.0f / fmaxf((float)dg, 1.0f);
  float z[8];
  const float4 sb0 = *(const float4*)(s0b + (size_t)i * HID + sl * 8);
  const float4 sb1 = *(const float4*)(s0b + (size_t)i * HID + sl * 8 + 4);
  z[0] = sb0.x + acc[0] * inv; z[1] = sb0.y + acc[1] * inv;
  z[2] = sb0.z + acc[2] * inv; z[3] = sb0.w + acc[3] * inv;
  z[4] = sb1.x + acc[4] * inv; z[5] = sb1.y + acc[5] * inv;
  z[6] = sb1.z + acc[6] * inv; z[7] = sb1.w + acc[7] * inv;
  float pm = 0.f;
#pragma unroll
  for (int f = 0; f < 8; ++f) pm += z[f];
#pragma unroll
  for (int mk = 1; mk < 8; mk <<= 1) pm += __shfl_xor(pm, mk);
  const float mean = pm * (1.0f / 64.0f);
  float pv = 0.f;
#pragma unroll
  for (int f = 0; f < 8; ++f) {
    z[f] -= mean;
    pv += z[f] * z[f];
  }
#pragma unroll
  for (int mk = 1; mk < 8; mk <<= 1) pv += __shfl_xor(pv, mk);
  const float rstd = rsqrtf(pv * (1.0f / 64.0f) + LN_EPS);
  if (grp == 0) {
    const float4 gv0 = *(const float4*)(g + sl * 8);
    const float4 gv1 = *(const float4*)(g + sl * 8 + 4);
    const float4 bv0 = *(const float4*)(be + sl * 8);
    const float4 bv1 = *(const float4*)(be + sl * 8 + 4);
    float4 o0, o1;
    o0.x = fmaxf(z[0] * rstd * gv0.x + bv0.x, 0.f);
    o0.y = fmaxf(z[1] * rstd * gv0.y + bv0.y, 0.f);
    o0.z = fmaxf(z[2] * rstd * gv0.z + bv0.z, 0.f);
    o0.w = fmaxf(z[3] * rstd * gv0.w + bv0.w, 0.f);
    o1.x = fmaxf(z[4] * rstd * gv1.x + bv1.x, 0.f);
    o1.y = fmaxf(z[5] * rstd * gv1.y + bv1.y, 0.f);
    o1.z = fmaxf(z[6] * rstd * gv1.z + bv1.z, 0.f);
    o1.w = fmaxf(z[7] * rstd * gv1.w + bv1.w, 0.f);
    *(float4*)(h1 + (size_t)i * HID + sl * 8) = o0;
    *(float4*)(h1 + (size_t)i * HID + sl * 8 + 4) = o1;
  }
}

// ------- Fused layer-1 aggregate + mean + LN + ReLU -> out (4 nodes/wave) ---
// lane = [q:2][grp:2][sl:2]; grid exact.
__global__ __launch_bounds__(256) void aggc1(
    const int* __restrict__ sortedSrc, const int* __restrict__ off,
    const int* __restrict__ deg, const unsigned short* __restrict__ p1u,
    const float* __restrict__ s1b, const float* __restrict__ g,
    const float* __restrict__ be, float* __restrict__ out) {
  const int lane = threadIdx.x & 63;
  const int q4 = lane >> 4;         // node quarter
  const int grp = (lane >> 2) & 3;  // 4 edge groups
  const int sl = lane & 3;          // 4 feature slices
  const int i = blockIdx.x * 16 + ((threadIdx.x >> 6) << 2) + q4;
  const int st = off[i];
  const int dg = deg[i];
  int dm = max(dg, __shfl_xor(dg, 16));
  const int dgmax = max(dm, __shfl_xor(dm, 32));
  float acc[8];
#pragma unroll
  for (int f = 0; f < 8; ++f) acc[f] = 0.f;

  for (int base = 0; base < dgmax; base += 16) {
    const int cnt = min(16, dg - base);
    const int l4 = lane & 15;
    const int idx = (l4 < cnt) ? sortedSrc[st + base + l4] : 0;
    const int cntmax = min(16, dgmax - base);
    for (int j = 0; j * 4 < cntmax; ++j) {
      const int e = j * 4 + grp;
      const float msk = (e < cnt) ? 1.f : 0.f;
      const int es = max(min(e, cnt - 1), 0);
      const int srcn = __shfl(idx, (q4 << 4) | es);
      const uint4 qv = *(const uint4*)(p1u + (size_t)srcn * OUT_DIM + sl * 8);
      acc[0] = fmaf(msk, uflo(qv.x), acc[0]);
      acc[1] = fmaf(msk, ufhi(qv.x), acc[1]);
      acc[2] = fmaf(msk, uflo(qv.y), acc[2]);
      acc[3] = fmaf(msk, ufhi(qv.y), acc[3]);
      acc[4] = fmaf(msk, uflo(qv.z), acc[4]);
      acc[5] = fmaf(msk, ufhi(qv.z), acc[5]);
      acc[6] = fmaf(msk, uflo(qv.w), acc[6]);
      acc[7] = fmaf(msk, ufhi(qv.w), acc[7]);
    }
  }
  // fold edge groups (xor over lane bits 2,3 — stays within node quarter)
#pragma unroll
  for (int mk = 4; mk < 16; mk <<= 1) {
#pragma unroll
    for (int f = 0; f < 8; ++f) acc[f] += __shfl_xor(acc[f], mk);
  }
  const float inv = 1.0f / fmaxf((float)dg, 1.0f);
  float z[8];
  const float4 sb0 = *(const float4*)(s1b + (size_t)i * OUT_DIM + sl * 8);
  const float4 sb1 = *(const float4*)(s1b + (size_t)i * OUT_DIM + sl * 8 + 4);
  z[0] = sb0.x + acc[0] * inv; z[1] = sb0.y + acc[1] * inv;
  z[2] = sb0.z + acc[2] * inv; z[3] = sb0.w + acc[3] * inv;
  z[4] = sb1.x + acc[4] * inv; z[5] = sb1.y + acc[5] * inv;
  z[6] = sb1.z + acc[6] * inv; z[7] = sb1.w + acc[7] * inv;
  float pm = 0.f;
#pragma unroll
  for (int f = 0; f < 8; ++f) pm += z[f];
#pragma unroll
  for (int mk = 1; mk < 4; mk <<= 1) pm += __shfl_xor(pm, mk);
  const float mean = pm * (1.0f / 32.0f);
  float pv = 0.f;
#pragma unroll
  for (int f = 0; f < 8; ++f) {
    z[f] -= mean;
    pv += z[f] * z[f];
  }
#pragma unroll
  for (int mk = 1; mk < 4; mk <<= 1) pv += __shfl_xor(pv, mk);
  const float rstd = rsqrtf(pv * (1.0f / 32.0f) + LN_EPS);
  if (grp == 0) {
    const float4 gv0 = *(const float4*)(g + sl * 8);
    const float4 gv1 = *(const float4*)(g + sl * 8 + 4);
    const float4 bv0 = *(const float4*)(be + sl * 8);
    const float4 bv1 = *(const float4*)(be + sl * 8 + 4);
    float4 o0, o1;
    o0.x = fmaxf(z[0] * rstd * gv0.x + bv0.x, 0.f);
    o0.y = fmaxf(z[1] * rstd * gv0.y + bv0.y, 0.f);
    o0.z = fmaxf(z[2] * rstd * gv0.z + bv0.z, 0.f);
    o0.w = fmaxf(z[3] * rstd * gv0.w + bv0.w, 0.f);
    o1.x = fmaxf(z[4] * rstd * gv1.x + bv1.x, 0.f);
    o1.y = fmaxf(z[5] * rstd * gv1.y + bv1.y, 0.f);
    o1.z = fmaxf(z[6] * rstd * gv1.z + bv1.z, 0.f);
    o1.w = fmaxf(z[7] * rstd * gv1.w + bv1.w, 0.f);
    *(float4*)(out + (size_t)i * OUT_DIM + sl * 8) = o0;
    *(float4*)(out + (size_t)i * OUT_DIM + sl * 8 + 4) = o1;
  }
}

extern "C" void kernel_launch(void* const* d_in, const int* in_sizes, int n_in,
                              void* d_out, int out_size, void* d_ws, size_t ws_size,
                              hipStream_t stream) {
  const float* x       = (const float*)d_in[0];
  const int*   edges   = (const int*)d_in[1];
  const float* Wself0  = (const float*)d_in[2];
  const float* Wneigh0 = (const float*)d_in[3];
  const float* b0      = (const float*)d_in[4];
  const float* g0      = (const float*)d_in[5];
  const float* be0     = (const float*)d_in[6];
  const float* Wself1  = (const float*)d_in[7];
  const float* Wneigh1 = (const float*)d_in[8];
  const float* b1      = (const float*)d_in[9];
  const float* g1      = (const float*)d_in[10];
  const float* be1     = (const float*)d_in[11];

  int* flag      = (int*)d_ws;                    // 64
  int* gcount    = flag + 64;                     // 1024 (padded)
  int* gbase     = gcount + 1024;                 // 1024 (padded)
  int* blkbase   = gbase + 1024;                  // NPBLK*NBKT = 391000
  int* deg       = blkbase + 400000;              // 100000
  int* off       = deg + N_NODES;                 // 100000
  int* sortedSrc = off + N_NODES;                 // 1.6M
  int2* pe       = (int2*)(sortedSrc + N_EDGES);  // 1.6M int2
  unsigned short* B0h = (unsigned short*)(pe + N_EDGES);
  unsigned short* B0l = B0h + 128 * 128;
  unsigned short* B1h = B0l + 128 * 128;
  unsigned short* B1l = B1h + 64 * 64;
  unsigned short* p0u = B1l + 64 * 64;
  float* s0b = (float*)(p0u + (size_t)N_NODES * HID);
  float* h1  = s0b + (size_t)N_NODES * HID;
  unsigned short* p1u = p0u;  // overlay (p0 dead)
  float* s1b = s0b;           // overlay (s0b dead)

  hipMemsetAsync(gcount, 0, NBKT * sizeof(int), stream);

  detect_edges<<<1, 256, 0, stream>>>(edges, flag);
  convW<<<80, 256, 0, stream>>>(Wneigh0, Wself0, Wneigh1, Wself1,
                                B0h, B0l, B1h, B1l);
  g0pc<<<NPBLK + G0BLK, 256, 0, stream>>>(x, B0h, B0l, b0, p0u, s0b,
                                          edges, flag, gcount, blkbase);
  part_scan<<<1, 256, 0, stream>>>(gcount, gbase);
  part_scatter<<<NPBLK, 256, 0, stream>>>(edges, flag, gbase, blkbase, pe);
  bucket_csr<<<NBKT, 256, 0, stream>>>(pe, gbase, gcount, deg, off, sortedSrc);

  aggc0<<<(N_NODES + 7) / 8, 256, 0, stream>>>(sortedSrc, off, deg, p0u, s0b,
                                               g0, be0, h1);
  gemm1<<<(N_NODES + 63) / 64, 256, 0, stream>>>(h1, B1h, B1l, b1, p1u, s1b);
  aggc1<<<(N_NODES + 15) / 16, 256, 0, stream>>>(sortedSrc, off, deg, p1u, s1b,
                                                 g1, be1, (float*)d_out);
}

// Round 9
// 161.261 us; speedup vs baseline: 4.5716x; 1.0845x over previous
//
#include <hip/hip_runtime.h>
#include <hip/hip_bf16.h>

#define N_NODES 100000
#define N_EDGES 1600000
#define IN_DIM 128
#define HID 64
#define OUT_DIM 32
#define LN_EPS 1e-5f
#define NBKT 782            // ceil(100000/128) coarse buckets (128 nodes each)
#define NPBLK 500           // partition blocks
#define PAIRS_PER_BLK 1600  // 500*1600*2 = 1.6M edges
#define G0BLK 1563          // gemm0 blocks: ceil(100000/64)

typedef __attribute__((ext_vector_type(8))) _Float16 half8;
typedef __attribute__((ext_vector_type(4))) float f32x4;

__device__ __forceinline__ float uf(unsigned short u) {
  return __uint_as_float(((unsigned int)u) << 16);
}
__device__ __forceinline__ float uflo(unsigned int u) {
  return __uint_as_float(u << 16);
}
__device__ __forceinline__ float ufhi(unsigned int u) {
  return __uint_as_float(u & 0xffff0000u);
}
__device__ __forceinline__ unsigned short bf16rne(float f) {
  unsigned int u = __float_as_uint(f);
  unsigned int r = u + 0x7fffu + ((u >> 16) & 1u);
  return (unsigned short)(r >> 16);
}

// ---------- Edge dtype detect: int64 (high words all 0) vs int32 ------------
__global__ void detect_edges(const int* __restrict__ w, int* __restrict__ flag) {
  __shared__ int any;
  if (threadIdx.x == 0) any = 0;
  __syncthreads();
  if (w[2 * threadIdx.x + 1] != 0) any = 1;
  __syncthreads();
  if (threadIdx.x == 0) flag[0] = any ? 0 : 1;  // 1 => int64 layout
}

// ---------- Weight convert to fp16: B0 [128n][128k], B1 [64n][64k] ----------
__global__ __launch_bounds__(256) void convW(
    const float* __restrict__ Wn0, const float* __restrict__ Ws0,
    const float* __restrict__ Wn1, const float* __restrict__ Ws1,
    _Float16* __restrict__ B0f, _Float16* __restrict__ B1f) {
  const int i = blockIdx.x * 256 + threadIdx.x;
  if (i < 128 * 128) {
    const int n = i >> 7, k = i & 127;
    const float w = (n < 64) ? Wn0[k * 64 + n] : Ws0[k * 64 + (n - 64)];
    B0f[i] = (_Float16)w;
  } else if (i < 128 * 128 + 64 * 64) {
    const int j = i - 128 * 128;
    const int n = j >> 6, k = j & 63;
    const float w = (n < 32) ? Wn1[k * 32 + n] : Ws1[k * 32 + (n - 32)];
    B1f[j] = (_Float16)w;
  }
}

// ---------- FUSED: part_count (blocks 0..499) || gemm0 (blocks 500..2062) ---
// part_count: coarse histogram + coalesced reservation (uses lb as scratch).
// gemm0: [p0 | s0b] = x @ [Wneigh0 | Wself0] (+b0), fp16 single-pass MFMA.
__global__ __launch_bounds__(256) void g0pc(
    const float* __restrict__ x, const _Float16* __restrict__ B0f,
    const float* __restrict__ b0,
    unsigned short* __restrict__ p0u, float* __restrict__ s0b,
    const int* __restrict__ w, const int* __restrict__ flag,
    int* __restrict__ gcount, int* __restrict__ blkbase) {
  __shared__ _Float16 lb[128 * 128];  // 32 KB (pc: int hist scratch)
  const int tid = threadIdx.x;

  if (blockIdx.x < NPBLK) {
    // ---------------- part_count path ----------------
    int* h = (int*)lb;
    const int b = blockIdx.x;
    for (int i = tid; i < NBKT; i += 256) h[i] = 0;
    __syncthreads();
    const int i64 = flag[0];
    const int pEnd = (b + 1) * PAIRS_PER_BLK;
    for (int p = b * PAIRS_PER_BLK + tid; p < pEnd; p += 256) {
      int d0, d1;
      if (i64) {
        const int4 vd = *(const int4*)(w + 2 * (size_t)N_EDGES + 4 * (size_t)p);
        d0 = vd.x; d1 = vd.z;
      } else {
        const int2 vd = *(const int2*)(w + (size_t)N_EDGES + 2 * (size_t)p);
        d0 = vd.x; d1 = vd.y;
      }
      atomicAdd(&h[d0 >> 7], 1);
      atomicAdd(&h[d1 >> 7], 1);
    }
    __syncthreads();
    for (int i = tid; i < NBKT; i += 256)
      blkbase[b * NBKT + i] = atomicAdd(&gcount[i], h[i]);  // coalesced
    return;
  }

  // ---------------- gemm0 path ----------------
  {
    const uint4* gb = (const uint4*)B0f;
    for (int i = tid; i < 2048; i += 256) {
      const int o = i << 4;
      const int sw = o ^ (((o >> 8) & 7) << 4);
      *(uint4*)((char*)lb + sw) = gb[i];
    }
  }
  __syncthreads();
  const int lane = tid & 63;
  const int wave = tid >> 6;
  const int rowbase = (blockIdx.x - NPBLK) * 64 + wave * 16;
  const int arow = rowbase + (lane & 15);
  const int rclamp = (arow < N_NODES) ? arow : 0;
  const int ko = (lane >> 4) << 3;  // 0,8,16,24

  f32x4 acc[8];
#pragma unroll
  for (int ct = 0; ct < 8; ++ct) acc[ct] = (f32x4){0.f, 0.f, 0.f, 0.f};

  for (int ks = 0; ks < 4; ++ks) {
    float av[8];
    const float* ax = x + (size_t)rclamp * IN_DIM + ks * 32 + ko;
    *(float4*)&av[0] = *(const float4*)ax;
    *(float4*)&av[4] = *(const float4*)(ax + 4);
    half8 ah;
#pragma unroll
    for (int j = 0; j < 8; ++j) ah[j] = (_Float16)av[j];
    const int kb = ks * 64 + (ko << 1);
#pragma unroll
    for (int ct = 0; ct < 8; ++ct) {
      const int n = ct * 16 + (lane & 15);
      const int boff = (n << 8) + kb;
      const int sb = boff ^ (((boff >> 8) & 7) << 4);
      const half8 bv = *(const half8*)((const char*)lb + sb);
      acc[ct] = __builtin_amdgcn_mfma_f32_16x16x32_f16(ah, bv, acc[ct], 0, 0, 0);
    }
  }
  const int rb4 = rowbase + ((lane >> 4) << 2);
  const int cc = lane & 15;
#pragma unroll
  for (int ct = 0; ct < 4; ++ct) {  // -> p0 (bf16)
#pragma unroll
    for (int j = 0; j < 4; ++j) {
      const int r = rb4 + j;
      if (r < N_NODES) p0u[(size_t)r * HID + ct * 16 + cc] = bf16rne(acc[ct][j]);
    }
  }
#pragma unroll
  for (int ct = 4; ct < 8; ++ct) {  // -> s0b (fp32 + bias)
    const float bias = b0[(ct - 4) * 16 + cc];
#pragma unroll
    for (int j = 0; j < 4; ++j) {
      const int r = rb4 + j;
      if (r < N_NODES) s0b[(size_t)r * HID + (ct - 4) * 16 + cc] = acc[ct][j] + bias;
    }
  }
}

// ---------- Phase B: single-block exclusive scan of 782 bucket counts -------
__global__ __launch_bounds__(256) void part_scan(
    const int* __restrict__ gcount, int* __restrict__ gbase) {
  __shared__ int lds[256];
  const int t = threadIdx.x;
  int v[4];
  int s = 0;
#pragma unroll
  for (int j = 0; j < 4; ++j) {
    const int idx = t * 4 + j;
    v[j] = (idx < NBKT) ? gcount[idx] : 0;
    s += v[j];
  }
  lds[t] = s;
  __syncthreads();
  for (int o = 1; o < 256; o <<= 1) {
    const int val = (t >= o) ? lds[t - o] : 0;
    __syncthreads();
    lds[t] += val;
    __syncthreads();
  }
  int run = lds[t] - s;
#pragma unroll
  for (int j = 0; j < 4; ++j) {
    const int idx = t * 4 + j;
    if (idx < NBKT) gbase[idx] = run;
    run += v[j];
  }
}

// ---------- Phase C: scatter edges into coarse-bucket regions (LDS cursors) -
__global__ __launch_bounds__(256) void part_scatter(
    const int* __restrict__ w, const int* __restrict__ flag,
    const int* __restrict__ gbase, const int* __restrict__ blkbase,
    int2* __restrict__ pe) {
  __shared__ int cur[NBKT];
  const int t = threadIdx.x, b = blockIdx.x;
  for (int i = t; i < NBKT; i += 256)
    cur[i] = gbase[i] + blkbase[b * NBKT + i];
  __syncthreads();
  const int i64 = flag[0];
  const int pEnd = (b + 1) * PAIRS_PER_BLK;
  for (int p = b * PAIRS_PER_BLK + t; p < pEnd; p += 256) {
    int s0, s1, d0, d1;
    if (i64) {
      const int4 vs = *(const int4*)(w + 4 * (size_t)p);
      const int4 vd = *(const int4*)(w + 2 * (size_t)N_EDGES + 4 * (size_t)p);
      s0 = vs.x; s1 = vs.z;
      d0 = vd.x; d1 = vd.z;
    } else {
      const int2 vs = *(const int2*)(w + 2 * (size_t)p);
      const int2 vd = *(const int2*)(w + (size_t)N_EDGES + 2 * (size_t)p);
      s0 = vs.x; s1 = vs.y;
      d0 = vd.x; d1 = vd.y;
    }
    const int sl0 = atomicAdd(&cur[d0 >> 7], 1);
    pe[sl0] = make_int2(s0, d0);
    const int sl1 = atomicAdd(&cur[d1 >> 7], 1);
    pe[sl1] = make_int2(s1, d1);
  }
}

// ---------- Phase D: per-bucket CSR build entirely in LDS -------------------
__global__ __launch_bounds__(256) void bucket_csr(
    const int2* __restrict__ pe, const int* __restrict__ gbase,
    const int* __restrict__ gcount, int* __restrict__ deg,
    int* __restrict__ off, int* __restrict__ sortedSrc) {
  __shared__ int ldeg[128];
  __shared__ int loff[128];
  __shared__ int lcur[128];
  const int t = threadIdx.x;
  const int bkt = blockIdx.x;
  const int nbase = bkt << 7;
  const int ebase = gbase[bkt];
  const int cnt = gcount[bkt];
  if (t < 128) ldeg[t] = 0;
  __syncthreads();
  for (int e = t; e < cnt; e += 256) {
    const int2 sd = pe[ebase + e];
    atomicAdd(&ldeg[sd.y - nbase], 1);
  }
  __syncthreads();
  if (t < 128) loff[t] = ldeg[t];
  __syncthreads();
  for (int o = 1; o < 128; o <<= 1) {
    int v = 0;
    if (t >= o && t < 128) v = loff[t - o];
    __syncthreads();
    if (t < 128) loff[t] += v;
    __syncthreads();
  }
  if (t < 128) {
    const int ex = loff[t] - ldeg[t];
    lcur[t] = ex;
    const int n = nbase + t;
    if (n < N_NODES) {
      deg[n] = ldeg[t];
      off[n] = ebase + ex;
    }
  }
  __syncthreads();
  for (int e = t; e < cnt; e += 256) {
    const int2 sd = pe[ebase + e];
    const int p = atomicAdd(&lcur[sd.y - nbase], 1);
    sortedSrc[ebase + p] = sd.x;
  }
}

// ------- Layer 1 fp16 MFMA GEMM: [p1 | s1b] = h1 @ [Wneigh1 | Wself1] (+b1) -
__global__ __launch_bounds__(256) void gemm1(
    const float* __restrict__ h1, const _Float16* __restrict__ B1f,
    const float* __restrict__ b1,
    unsigned short* __restrict__ p1u, float* __restrict__ s1b) {
  __shared__ _Float16 lb[64 * 64];  // 8 KB
  const int tid = threadIdx.x;
  {
    const uint4* gb = (const uint4*)B1f;
    for (int i = tid; i < 512; i += 256) {
      const int o = i << 4;
      const int sw = o ^ (((o >> 7) & 7) << 4);
      *(uint4*)((char*)lb + sw) = gb[i];
    }
  }
  __syncthreads();
  const int lane = tid & 63;
  const int wave = tid >> 6;
  const int rowbase = blockIdx.x * 64 + wave * 16;
  const int arow = rowbase + (lane & 15);
  const int rclamp = (arow < N_NODES) ? arow : 0;
  const int ko = (lane >> 4) << 3;

  f32x4 acc[4];
#pragma unroll
  for (int ct = 0; ct < 4; ++ct) acc[ct] = (f32x4){0.f, 0.f, 0.f, 0.f};

  for (int ks = 0; ks < 2; ++ks) {
    float av[8];
    const float* ax = h1 + (size_t)rclamp * HID + ks * 32 + ko;
    *(float4*)&av[0] = *(const float4*)ax;
    *(float4*)&av[4] = *(const float4*)(ax + 4);
    half8 ah;
#pragma unroll
    for (int j = 0; j < 8; ++j) ah[j] = (_Float16)av[j];
    const int kb = ks * 64 + (ko << 1);
#pragma unroll
    for (int ct = 0; ct < 4; ++ct) {
      const int n = ct * 16 + (lane & 15);
      const int boff = (n << 7) + kb;
      const int sb = boff ^ (((boff >> 7) & 7) << 4);
      const half8 bv = *(const half8*)((const char*)lb + sb);
      acc[ct] = __builtin_amdgcn_mfma_f32_16x16x32_f16(ah, bv, acc[ct], 0, 0, 0);
    }
  }
  const int rb4 = rowbase + ((lane >> 4) << 2);
  const int cc = lane & 15;
#pragma unroll
  for (int ct = 0; ct < 2; ++ct) {  // -> p1 (bf16)
#pragma unroll
    for (int j = 0; j < 4; ++j) {
      const int r = rb4 + j;
      if (r < N_NODES) p1u[(size_t)r * OUT_DIM + ct * 16 + cc] = bf16rne(acc[ct][j]);
    }
  }
#pragma unroll
  for (int ct = 2; ct < 4; ++ct) {  // -> s1b (fp32 + bias)
    const float bias = b1[(ct - 2) * 16 + cc];
#pragma unroll
    for (int j = 0; j < 4; ++j) {
      const int r = rb4 + j;
      if (r < N_NODES)
        s1b[(size_t)r * OUT_DIM + (ct - 2) * 16 + cc] = acc[ct][j] + bias;
    }
  }
}

// ------- Fused layer-0 aggregate + mean + LN + ReLU -> h1 (2 nodes/wave) ----
// lane = [h:1][grp:2][sl:3]; grid exact (no early return: shuffles wave-wide).
__global__ __launch_bounds__(256) void aggc0(
    const int* __restrict__ sortedSrc, const int* __restrict__ off,
    const int* __restrict__ deg, const unsigned short* __restrict__ p0u,
    const float* __restrict__ s0b, const float* __restrict__ g,
    const float* __restrict__ be, float* __restrict__ h1) {
  const int lane = threadIdx.x & 63;
  const int h = lane >> 5;          // node half
  const int grp = (lane >> 3) & 3;  // 4 edge groups
  const int sl = lane & 7;          // 8 feature slices
  const int i = blockIdx.x * 8 + ((threadIdx.x >> 6) << 1) + h;
  const int st = off[i];
  const int dg = deg[i];
  const int dgmax = max(dg, __shfl_xor(dg, 32));
  float acc[8];
#pragma unroll
  for (int f = 0; f < 8; ++f) acc[f] = 0.f;

  for (int base = 0; base < dgmax; base += 32) {
    const int cnt = min(32, dg - base);  // can be <= 0 for shorter node
    const int l5 = lane & 31;
    const int idx = (l5 < cnt) ? sortedSrc[st + base + l5] : 0;
    const int cntmax = min(32, dgmax - base);
    for (int j = 0; j * 4 < cntmax; ++j) {
      const int e = j * 4 + grp;
      const float msk = (e < cnt) ? 1.f : 0.f;
      const int es = max(min(e, cnt - 1), 0);
      const int srcn = __shfl(idx, (h << 5) | es);
      const uint4 q = *(const uint4*)(p0u + (size_t)srcn * HID + sl * 8);
      acc[0] = fmaf(msk, uflo(q.x), acc[0]);
      acc[1] = fmaf(msk, ufhi(q.x), acc[1]);
      acc[2] = fmaf(msk, uflo(q.y), acc[2]);
      acc[3] = fmaf(msk, ufhi(q.y), acc[3]);
      acc[4] = fmaf(msk, uflo(q.z), acc[4]);
      acc[5] = fmaf(msk, ufhi(q.z), acc[5]);
      acc[6] = fmaf(msk, uflo(q.w), acc[6]);
      acc[7] = fmaf(msk, ufhi(q.w), acc[7]);
    }
  }
  // fold edge groups (xor over lane bits 3,4 — stays within node half)
#pragma unroll
  for (int mk = 8; mk < 32; mk <<= 1) {
#pragma unroll
    for (int f = 0; f < 8; ++f) acc[f] += __shfl_xor(acc[f], mk);
  }
  const float inv = 1.0f / fmaxf((float)dg, 1.0f);
  float z[8];
  const float4 sb0 = *(const float4*)(s0b + (size_t)i * HID + sl * 8);
  const float4 sb1 = *(const float4*)(s0b + (size_t)i * HID + sl * 8 + 4);
  z[0] = sb0.x + acc[0] * inv; z[1] = sb0.y + acc[1] * inv;
  z[2] = sb0.z + acc[2] * inv; z[3] = sb0.w + acc[3] * inv;
  z[4] = sb1.x + acc[4] * inv; z[5] = sb1.y + acc[5] * inv;
  z[6] = sb1.z + acc[6] * inv; z[7] = sb1.w + acc[7] * inv;
  float pm = 0.f;
#pragma unroll
  for (int f = 0; f < 8; ++f) pm += z[f];
#pragma unroll
  for (int mk = 1; mk < 8; mk <<= 1) pm += __shfl_xor(pm, mk);
  const float mean = pm * (1.0f / 64.0f);
  float pv = 0.f;
#pragma unroll
  for (int f = 0; f < 8; ++f) {
    z[f] -= mean;
    pv += z[f] * z[f];
  }
#pragma unroll
  for (int mk = 1; mk < 8; mk <<= 1) pv += __shfl_xor(pv, mk);
  const float rstd = rsqrtf(pv * (1.0f / 64.0f) + LN_EPS);
  if (grp == 0) {
    const float4 gv0 = *(const float4*)(g + sl * 8);
    const float4 gv1 = *(const float4*)(g + sl * 8 + 4);
    const float4 bv0 = *(const float4*)(be + sl * 8);
    const float4 bv1 = *(const float4*)(be + sl * 8 + 4);
    float4 o0, o1;
    o0.x = fmaxf(z[0] * rstd * gv0.x + bv0.x, 0.f);
    o0.y = fmaxf(z[1] * rstd * gv0.y + bv0.y, 0.f);
    o0.z = fmaxf(z[2] * rstd * gv0.z + bv0.z, 0.f);
    o0.w = fmaxf(z[3] * rstd * gv0.w + bv0.w, 0.f);
    o1.x = fmaxf(z[4] * rstd * gv1.x + bv1.x, 0.f);
    o1.y = fmaxf(z[5] * rstd * gv1.y + bv1.y, 0.f);
    o1.z = fmaxf(z[6] * rstd * gv1.z + bv1.z, 0.f);
    o1.w = fmaxf(z[7] * rstd * gv1.w + bv1.w, 0.f);
    *(float4*)(h1 + (size_t)i * HID + sl * 8) = o0;
    *(float4*)(h1 + (size_t)i * HID + sl * 8 + 4) = o1;
  }
}

// ------- Fused layer-1 aggregate + mean + LN + ReLU -> out (4 nodes/wave) ---
// lane = [q:2][grp:2][sl:2]; grid exact.
__global__ __launch_bounds__(256) void aggc1(
    const int* __restrict__ sortedSrc, const int* __restrict__ off,
    const int* __restrict__ deg, const unsigned short* __restrict__ p1u,
    const float* __restrict__ s1b, const float* __restrict__ g,
    const float* __restrict__ be, float* __restrict__ out) {
  const int lane = threadIdx.x & 63;
  const int q4 = lane >> 4;         // node quarter
  const int grp = (lane >> 2) & 3;  // 4 edge groups
  const int sl = lane & 3;          // 4 feature slices
  const int i = blockIdx.x * 16 + ((threadIdx.x >> 6) << 2) + q4;
  const int st = off[i];
  const int dg = deg[i];
  int dm = max(dg, __shfl_xor(dg, 16));
  const int dgmax = max(dm, __shfl_xor(dm, 32));
  float acc[8];
#pragma unroll
  for (int f = 0; f < 8; ++f) acc[f] = 0.f;

  for (int base = 0; base < dgmax; base += 16) {
    const int cnt = min(16, dg - base);
    const int l4 = lane & 15;
    const int idx = (l4 < cnt) ? sortedSrc[st + base + l4] : 0;
    const int cntmax = min(16, dgmax - base);
    for (int j = 0; j * 4 < cntmax; ++j) {
      const int e = j * 4 + grp;
      const float msk = (e < cnt) ? 1.f : 0.f;
      const int es = max(min(e, cnt - 1), 0);
      const int srcn = __shfl(idx, (q4 << 4) | es);
      const uint4 qv = *(const uint4*)(p1u + (size_t)srcn * OUT_DIM + sl * 8);
      acc[0] = fmaf(msk, uflo(qv.x), acc[0]);
      acc[1] = fmaf(msk, ufhi(qv.x), acc[1]);
      acc[2] = fmaf(msk, uflo(qv.y), acc[2]);
      acc[3] = fmaf(msk, ufhi(qv.y), acc[3]);
      acc[4] = fmaf(msk, uflo(qv.z), acc[4]);
      acc[5] = fmaf(msk, ufhi(qv.z), acc[5]);
      acc[6] = fmaf(msk, uflo(qv.w), acc[6]);
      acc[7] = fmaf(msk, ufhi(qv.w), acc[7]);
    }
  }
  // fold edge groups (xor over lane bits 2,3 — stays within node quarter)
#pragma unroll
  for (int mk = 4; mk < 16; mk <<= 1) {
#pragma unroll
    for (int f = 0; f < 8; ++f) acc[f] += __shfl_xor(acc[f], mk);
  }
  const float inv = 1.0f / fmaxf((float)dg, 1.0f);
  float z[8];
  const float4 sb0 = *(const float4*)(s1b + (size_t)i * OUT_DIM + sl * 8);
  const float4 sb1 = *(const float4*)(s1b + (size_t)i * OUT_DIM + sl * 8 + 4);
  z[0] = sb0.x + acc[0] * inv; z[1] = sb0.y + acc[1] * inv;
  z[2] = sb0.z + acc[2] * inv; z[3] = sb0.w + acc[3] * inv;
  z[4] = sb1.x + acc[4] * inv; z[5] = sb1.y + acc[5] * inv;
  z[6] = sb1.z + acc[6] * inv; z[7] = sb1.w + acc[7] * inv;
  float pm = 0.f;
#pragma unroll
  for (int f = 0; f < 8; ++f) pm += z[f];
#pragma unroll
  for (int mk = 1; mk < 4; mk <<= 1) pm += __shfl_xor(pm, mk);
  const float mean = pm * (1.0f / 32.0f);
  float pv = 0.f;
#pragma unroll
  for (int f = 0; f < 8; ++f) {
    z[f] -= mean;
    pv += z[f] * z[f];
  }
#pragma unroll
  for (int mk = 1; mk < 4; mk <<= 1) pv += __shfl_xor(pv, mk);
  const float rstd = rsqrtf(pv * (1.0f / 32.0f) + LN_EPS);
  if (grp == 0) {
    const float4 gv0 = *(const float4*)(g + sl * 8);
    const float4 gv1 = *(const float4*)(g + sl * 8 + 4);
    const float4 bv0 = *(const float4*)(be + sl * 8);
    const float4 bv1 = *(const float4*)(be + sl * 8 + 4);
    float4 o0, o1;
    o0.x = fmaxf(z[0] * rstd * gv0.x + bv0.x, 0.f);
    o0.y = fmaxf(z[1] * rstd * gv0.y + bv0.y, 0.f);
    o0.z = fmaxf(z[2] * rstd * gv0.z + bv0.z, 0.f);
    o0.w = fmaxf(z[3] * rstd * gv0.w + bv0.w, 0.f);
    o1.x = fmaxf(z[4] * rstd * gv1.x + bv1.x, 0.f);
    o1.y = fmaxf(z[5] * rstd * gv1.y + bv1.y, 0.f);
    o1.z = fmaxf(z[6] * rstd * gv1.z + bv1.z, 0.f);
    o1.w = fmaxf(z[7] * rstd * gv1.w + bv1.w, 0.f);
    *(float4*)(out + (size_t)i * OUT_DIM + sl * 8) = o0;
    *(float4*)(out + (size_t)i * OUT_DIM + sl * 8 + 4) = o1;
  }
}

extern "C" void kernel_launch(void* const* d_in, const int* in_sizes, int n_in,
                              void* d_out, int out_size, void* d_ws, size_t ws_size,
                              hipStream_t stream) {
  const float* x       = (const float*)d_in[0];
  const int*   edges   = (const int*)d_in[1];
  const float* Wself0  = (const float*)d_in[2];
  const float* Wneigh0 = (const float*)d_in[3];
  const float* b0      = (const float*)d_in[4];
  const float* g0      = (const float*)d_in[5];
  const float* be0     = (const float*)d_in[6];
  const float* Wself1  = (const float*)d_in[7];
  const float* Wneigh1 = (const float*)d_in[8];
  const float* b1      = (const float*)d_in[9];
  const float* g1      = (const float*)d_in[10];
  const float* be1     = (const float*)d_in[11];

  int* flag      = (int*)d_ws;                    // 64
  int* gcount    = flag + 64;                     // 1024 (padded)
  int* gbase     = gcount + 1024;                 // 1024 (padded)
  int* blkbase   = gbase + 1024;                  // NPBLK*NBKT = 391000
  int* deg       = blkbase + 400000;              // 100000
  int* off       = deg + N_NODES;                 // 100000
  int* sortedSrc = off + N_NODES;                 // 1.6M
  int2* pe       = (int2*)(sortedSrc + N_EDGES);  // 1.6M int2
  _Float16* B0f  = (_Float16*)(pe + N_EDGES);     // 16384 halfs
  _Float16* B1f  = B0f + 128 * 128;               // 4096 halfs
  unsigned short* p0u = (unsigned short*)(B1f + 64 * 64);
  float* s0b = (float*)(p0u + (size_t)N_NODES * HID);
  float* h1  = s0b + (size_t)N_NODES * HID;
  unsigned short* p1u = p0u;  // overlay (p0 dead)
  float* s1b = s0b;           // overlay (s0b dead)

  hipMemsetAsync(gcount, 0, NBKT * sizeof(int), stream);

  detect_edges<<<1, 256, 0, stream>>>(edges, flag);
  convW<<<80, 256, 0, stream>>>(Wneigh0, Wself0, Wneigh1, Wself1, B0f, B1f);
  g0pc<<<NPBLK + G0BLK, 256, 0, stream>>>(x, B0f, b0, p0u, s0b,
                                          edges, flag, gcount, blkbase);
  part_scan<<<1, 256, 0, stream>>>(gcount, gbase);
  part_scatter<<<NPBLK, 256, 0, stream>>>(edges, flag, gbase, blkbase, pe);
  bucket_csr<<<NBKT, 256, 0, stream>>>(pe, gbase, gcount, deg, off, sortedSrc);

  aggc0<<<(N_NODES + 7) / 8, 256, 0, stream>>>(sortedSrc, off, deg, p0u, s0b,
                                               g0, be0, h1);
  gemm1<<<(N_NODES + 63) / 64, 256, 0, stream>>>(h1, B1f, b1, p1u, s1b);
  aggc1<<<(N_NODES + 15) / 16, 256, 0, stream>>>(sortedSrc, off, deg, p1u, s1b,
                                                 g1, be1, (float*)d_out);
}